// Round 3
// baseline (373.953 us; speedup 1.0000x reference)
//
#include <hip/hip_runtime.h>
#include <hip/hip_bf16.h>

#define B_  2
#define S_  2048
#define H_  1024
#define NH_ 16
#define HD_ 64
#define T_  (B_*S_)     // 4096 tokens
#define H3_ (3*H_)      // 3072

typedef float  floatx4 __attribute__((ext_vector_type(4)));
typedef __bf16 bf16x8  __attribute__((ext_vector_type(8)));

__device__ inline unsigned short f2bf_rn(float f) {
    union { float f; unsigned int u; } v; v.f = f;
    unsigned int u = v.u;
    u += 0x7fffu + ((u >> 16) & 1u);
    return (unsigned short)(u >> 16);
}
__device__ inline floatx4 fzero4() { floatx4 v; v[0]=0.f; v[1]=0.f; v[2]=0.f; v[3]=0.f; return v; }

// ---------------------------------------------------------------- fused cast + transpose: W[K][N] f32 -> Wt[N][K] bf16
#define TLD 72
__global__ __launch_bounds__(256) void cvt_transpose_k(const float* __restrict__ W,
                                                       unsigned short* __restrict__ Wt,
                                                       int K, int N) {
    __shared__ unsigned short Ts[64 * TLD];
    const int nb = blockIdx.x * 64;
    const int kb = blockIdx.y * 64;
    const int tid = threadIdx.x;
    #pragma unroll
    for (int p = 0; p < 4; p++) {
        const int krow = kb + p * 16 + (tid >> 4);
        const int ncol = (tid & 15) * 4;
        const float4 w = *reinterpret_cast<const float4*>(&W[(size_t)krow * N + nb + ncol]);
        Ts[(ncol + 0) * TLD + p * 16 + (tid >> 4)] = f2bf_rn(w.x);
        Ts[(ncol + 1) * TLD + p * 16 + (tid >> 4)] = f2bf_rn(w.y);
        Ts[(ncol + 2) * TLD + p * 16 + (tid >> 4)] = f2bf_rn(w.z);
        Ts[(ncol + 3) * TLD + p * 16 + (tid >> 4)] = f2bf_rn(w.w);
    }
    __syncthreads();
    #pragma unroll
    for (int p = 0; p < 2; p++) {
        const int n = (tid >> 3) + p * 32;
        const int k8 = (tid & 7) * 8;
        const uint4 v = *reinterpret_cast<const uint4*>(&Ts[n * TLD + k8]);
        *reinterpret_cast<uint4*>(&Wt[(size_t)(nb + n) * K + kb + k8]) = v;
    }
}

// ---------------------------------------------------------------- LayerNorm (fp32 stats, bf16 out)
__global__ __launch_bounds__(256) void layernorm_k(const float* __restrict__ x,
                                                   const float* __restrict__ w,
                                                   const float* __restrict__ b,
                                                   unsigned short* __restrict__ xn) {
    const int t   = blockIdx.x;
    const int tid = threadIdx.x;
    const float4 v = reinterpret_cast<const float4*>(x + (size_t)t * H_)[tid];
    float s  = v.x + v.y + v.z + v.w;
    float s2 = v.x*v.x + v.y*v.y + v.z*v.z + v.w*v.w;
    for (int off = 32; off > 0; off >>= 1) {
        s  += __shfl_down(s,  off, 64);
        s2 += __shfl_down(s2, off, 64);
    }
    __shared__ float red[8];
    const int wave = tid >> 6, lane = tid & 63;
    if (lane == 0) { red[wave] = s; red[4 + wave] = s2; }
    __syncthreads();
    if (tid == 0) {
        red[0] = red[0] + red[1] + red[2] + red[3];
        red[4] = red[4] + red[5] + red[6] + red[7];
    }
    __syncthreads();
    const float mean = red[0] * (1.f / H_);
    const float var  = red[4] * (1.f / H_) - mean * mean;
    const float rstd = rsqrtf(var + 1e-5f);
    const float4 wv = reinterpret_cast<const float4*>(w)[tid];
    const float4 bv = reinterpret_cast<const float4*>(b)[tid];
    ushort4 o = make_ushort4(f2bf_rn((v.x - mean) * rstd * wv.x + bv.x),
                             f2bf_rn((v.y - mean) * rstd * wv.y + bv.y),
                             f2bf_rn((v.z - mean) * rstd * wv.z + bv.z),
                             f2bf_rn((v.w - mean) * rstd * wv.w + bv.w));
    reinterpret_cast<ushort4*>(xn + (size_t)t * H_)[tid] = o;
}

// ---------------------------------------------------------------- bf16 MFMA GEMM  C = A(MxK) @ Bt(NxK)^T + bias
// 128x128 tile, BK=32, single-barrier ping-pong LDS, register prefetch.
#define BM 128
#define BN 128
#define BK 32
#define LDT 40

template <bool OUT_F32>
__global__ __launch_bounds__(256, 2) void gemm_bf16(const unsigned short* __restrict__ A,
                                                    const unsigned short* __restrict__ Bt,
                                                    const float* __restrict__ bias,
                                                    float* __restrict__ Cf,
                                                    unsigned short* __restrict__ Cb,
                                                    int M, int N, int K) {
    __shared__ unsigned short As[2][BM * LDT];
    __shared__ unsigned short Bs[2][BN * LDT];

    const int tid  = threadIdx.x;
    const int lane = tid & 63;
    const int wave = tid >> 6;
    const int wr = wave >> 1, wc = wave & 1;
    const int mBase = blockIdx.y * BM;
    const int nBase = blockIdx.x * BN;

    floatx4 acc[4][4];
    #pragma unroll
    for (int i = 0; i < 4; i++)
        #pragma unroll
        for (int j = 0; j < 4; j++) acc[i][j] = fzero4();

    const int arow = tid >> 2;        // 0..63
    const int acol = (tid & 3) * 8;   // 0,8,16,24
    const int mrow = lane & 15;
    const int koff = (lane >> 4) * 8;

    uint4 va[2], vb[2];
    auto gpf = [&](int kb) {
        #pragma unroll
        for (int p = 0; p < 2; p++) {
            const int r = arow + p * 64;
            va[p] = *reinterpret_cast<const uint4*>(&A [(size_t)(mBase + r) * K + kb + acol]);
            vb[p] = *reinterpret_cast<const uint4*>(&Bt[(size_t)(nBase + r) * K + kb + acol]);
        }
    };
    gpf(0);

    int buf = 0;
    for (int kb = 0; kb < K; kb += BK, buf ^= 1) {
        #pragma unroll
        for (int p = 0; p < 2; p++) {
            const int r = arow + p * 64;
            *reinterpret_cast<uint4*>(&As[buf][r * LDT + acol]) = va[p];
            *reinterpret_cast<uint4*>(&Bs[buf][r * LDT + acol]) = vb[p];
        }
        __syncthreads();
        if (kb + BK < K) gpf(kb + BK);

        bf16x8 afrag[4], bfrag[4];
        #pragma unroll
        for (int mt = 0; mt < 4; mt++)
            afrag[mt] = *reinterpret_cast<const bf16x8*>(&As[buf][(wr * 64 + mt * 16 + mrow) * LDT + koff]);
        #pragma unroll
        for (int nt = 0; nt < 4; nt++)
            bfrag[nt] = *reinterpret_cast<const bf16x8*>(&Bs[buf][(wc * 64 + nt * 16 + mrow) * LDT + koff]);
        #pragma unroll
        for (int mt = 0; mt < 4; mt++)
            #pragma unroll
            for (int nt = 0; nt < 4; nt++)
                acc[mt][nt] = __builtin_amdgcn_mfma_f32_16x16x32_bf16(afrag[mt], bfrag[nt], acc[mt][nt], 0, 0, 0);
    }

    const int col0 = lane & 15;
    const int r0   = (lane >> 4) * 4;
    #pragma unroll
    for (int mt = 0; mt < 4; mt++) {
        #pragma unroll
        for (int nt = 0; nt < 4; nt++) {
            const int gcol = nBase + wc * 64 + nt * 16 + col0;
            const float bs = bias[gcol];
            #pragma unroll
            for (int reg = 0; reg < 4; reg++) {
                const int grow = mBase + wr * 64 + mt * 16 + r0 + reg;
                const float v = acc[mt][nt][reg] + bs;
                if constexpr (OUT_F32) Cf[(size_t)grow * N + gcol] = v;
                else                   Cb[(size_t)grow * N + gcol] = f2bf_rn(v);
            }
        }
    }
}

// ---------------------------------------------------------------- rotary for q,k -> Q/K [b,h,s,d] bf16
__global__ __launch_bounds__(256) void rotary_qk_k(const unsigned short* __restrict__ qkv,
                                                   unsigned short* __restrict__ Q,
                                                   unsigned short* __restrict__ K) {
    const int t   = blockIdx.x;
    const int b   = t / S_;
    const int s   = t % S_;
    const int tid = threadIdx.x;
    const unsigned short* row = qkv + (size_t)t * H3_;
    #pragma unroll
    for (int i = 0; i < 4; i++) {
        const int idx = tid + i * 256;    // h*64 + d
        const int h = idx >> 6, d = idx & 63;
        const float inv_freq = __expf((float)(d & 31) * (-0.2878231366f)); // -ln(10000)/32
        const float fr = (float)s * inv_freq;
        float sn, cs;
        __sincosf(fr, &sn, &cs);
        const size_t dst = ((size_t)(b * NH_ + h) * S_ + s) * HD_ + d;
        {
            union { unsigned int u; float f; } a, p;
            a.u = ((unsigned int)row[idx]) << 16;
            p.u = ((unsigned int)row[idx ^ 32]) << 16;
            const float rot = (d < 32) ? -p.f : p.f;
            Q[dst] = f2bf_rn(a.f * cs + rot * sn);
        }
        {
            union { unsigned int u; float f; } a, p;
            a.u = ((unsigned int)row[H_ + idx]) << 16;
            p.u = ((unsigned int)row[H_ + (idx ^ 32)]) << 16;
            const float rot = (d < 32) ? -p.f : p.f;
            K[dst] = f2bf_rn(a.f * cs + rot * sn);
        }
    }
}

// ---------------------------------------------------------------- V transpose: qkv v-part -> Vt[bh][d][s]
__global__ __launch_bounds__(256) void v_transpose_k(const unsigned short* __restrict__ qkv,
                                                     unsigned short* __restrict__ Vt) {
    __shared__ unsigned short Vs[64 * TLD];
    const int s0 = blockIdx.x * 64;
    const int b  = blockIdx.y;
    const int tid = threadIdx.x;
    for (int h = 0; h < NH_; h++) {
        __syncthreads();
        #pragma unroll
        for (int p = 0; p < 2; p++) {
            const int tl = tid >> 2;
            const int c  = (tid & 3) * 8 + p * 32;
            const uint4 v = *reinterpret_cast<const uint4*>(
                &qkv[(size_t)(b * S_ + s0 + tl) * H3_ + 2 * H_ + h * 64 + c]);
            *reinterpret_cast<uint4*>(&Vs[tl * TLD + c]) = v;
        }
        __syncthreads();
        #pragma unroll
        for (int p = 0; p < 2; p++) {
            const int d  = (tid >> 3) + p * 32;
            const int s8 = (tid & 7) * 8;
            unsigned short tmp[8];
            #pragma unroll
            for (int jj = 0; jj < 8; jj++) tmp[jj] = Vs[(s8 + jj) * TLD + d];
            *reinterpret_cast<uint4*>(&Vt[((size_t)(b * NH_ + h) * HD_ + d) * S_ + s0 + s8]) =
                *reinterpret_cast<uint4*>(tmp);
        }
    }
}

// ---------------------------------------------------------------- flash attention, band-paired, ping-pong LDS
#define ALD 72

__global__ __launch_bounds__(256, 2) void attn_k(const unsigned short* __restrict__ Q,
                                                 const unsigned short* __restrict__ Kg,
                                                 const unsigned short* __restrict__ Vt,
                                                 const int* __restrict__ mask,
                                                 unsigned short* __restrict__ ctx) {
    // XCD swizzle: all 16 j-blocks of a head share id%8 -> same XCD (round-robin heuristic)
    const int id = blockIdx.x;              // 0..511
    const int bh = (id & 7) + 8 * (id >> 7);
    const int j  = (id >> 3) & 15;
    const int b  = bh >> 4;
    const int h  = bh & 15;
    const int tid  = threadIdx.x;
    const int lane = tid & 63;
    const int wave = tid >> 6;

    __shared__ unsigned short Ks [2][64 * ALD];
    __shared__ unsigned short Vts[2][64 * ALD];
    __shared__ unsigned short Ps[4][32 * ALD];

    const size_t base = (size_t)bh * S_ * HD_;
    const int qbase[2] = { j * 64 + wave * 16, (31 - j) * 64 + wave * 16 };
    const int mrow = lane & 15;
    const int koff = (lane >> 4) * 8;
    const int r0   = (lane >> 4) * 4;
    const int col0 = lane & 15;

    bf16x8 qf[2][2];
    #pragma unroll
    for (int m = 0; m < 2; m++)
        #pragma unroll
        for (int hh = 0; hh < 2; hh++)
            qf[m][hh] = *reinterpret_cast<const bf16x8*>(
                &Q[base + (size_t)(qbase[m] + mrow) * HD_ + hh * 32 + koff]);

    floatx4 Oacc[2][4];
    float m_i[2][4], l_i[2][4];
    #pragma unroll
    for (int m = 0; m < 2; m++) {
        #pragma unroll
        for (int nt = 0; nt < 4; nt++) Oacc[m][nt] = fzero4();
        #pragma unroll
        for (int r = 0; r < 4; r++) { m_i[m][r] = -1e30f; l_i[m][r] = 0.f; }
    }

    const int last = 31 - j;
    const int srow = tid >> 3;          // 0..31
    const int scol = (tid & 7) * 8;

    uint4 kreg[2], vreg[2];
    float mb_pf[4];
    auto prefetch = [&](int kt) {
        const int kb = kt * 64;
        #pragma unroll
        for (int p = 0; p < 2; p++) {
            kreg[p] = *reinterpret_cast<const uint4*>(&Kg[base + (size_t)(kb + srow + p * 32) * HD_ + scol]);
            vreg[p] = *reinterpret_cast<const uint4*>(&Vt[base + (size_t)(srow + p * 32) * S_ + kb + scol]);
        }
        #pragma unroll
        for (int nt = 0; nt < 4; nt++)
            mb_pf[nt] = (1.f - (float)mask[b * S_ + kb + nt * 16 + col0]) * (-10000.f);
    };
    prefetch(0);

    for (int kt = 0; kt <= last; kt++) {
        const int kb  = kt * 64;
        const int buf = kt & 1;
        unsigned short* ks = Ks [buf];
        unsigned short* vs = Vts[buf];
        #pragma unroll
        for (int p = 0; p < 2; p++) {
            *reinterpret_cast<uint4*>(&ks[(srow + p * 32) * ALD + scol]) = kreg[p];
            *reinterpret_cast<uint4*>(&vs[(srow + p * 32) * ALD + scol]) = vreg[p];
        }
        __syncthreads();
        float mb_c[4];
        #pragma unroll
        for (int nt = 0; nt < 4; nt++) mb_c[nt] = mb_pf[nt];
        if (kt < last) prefetch(kt + 1);

        const bool skip0 = (kt > j);
        unsigned short* pw = Ps[wave];

        #pragma unroll
        for (int m = 0; m < 2; m++) {
            if (m == 0 && skip0) continue;
            floatx4 sc[4];
            #pragma unroll
            for (int nt = 0; nt < 4; nt++) {
                const bf16x8 k0 = *reinterpret_cast<const bf16x8*>(&ks[(nt * 16 + mrow) * ALD + koff]);
                const bf16x8 k1 = *reinterpret_cast<const bf16x8*>(&ks[(nt * 16 + mrow) * ALD + 32 + koff]);
                floatx4 c = fzero4();
                c = __builtin_amdgcn_mfma_f32_16x16x32_bf16(qf[m][0], k0, c, 0, 0, 0);
                c = __builtin_amdgcn_mfma_f32_16x16x32_bf16(qf[m][1], k1, c, 0, 0, 0);
                sc[nt] = c;
            }
            const bool needc = (kb + 63) > qbase[m];
            float mt[4];
            #pragma unroll
            for (int r = 0; r < 4; r++) mt[r] = -1e30f;
            #pragma unroll
            for (int nt = 0; nt < 4; nt++)
                #pragma unroll
                for (int reg = 0; reg < 4; reg++) {
                    float sv = sc[nt][reg] * 0.125f + mb_c[nt];
                    if (needc) {
                        const int key = kb + nt * 16 + col0;
                        const int q   = qbase[m] + r0 + reg;
                        if (key > q) sv = -10000.f;
                    }
                    sc[nt][reg] = sv;
                    mt[reg] = fmaxf(mt[reg], sv);
                }
            #pragma unroll
            for (int off = 1; off < 16; off <<= 1)
                #pragma unroll
                for (int reg = 0; reg < 4; reg++)
                    mt[reg] = fmaxf(mt[reg], __shfl_xor(mt[reg], off, 64));
            float alpha[4], ls[4];
            #pragma unroll
            for (int reg = 0; reg < 4; reg++) {
                const float mn = fmaxf(m_i[m][reg], mt[reg]);
                alpha[reg] = __expf(m_i[m][reg] - mn);
                m_i[m][reg] = mn;
                ls[reg] = 0.f;
            }
            #pragma unroll
            for (int nt = 0; nt < 4; nt++)
                #pragma unroll
                for (int reg = 0; reg < 4; reg++) {
                    const float p = __expf(sc[nt][reg] - m_i[m][reg]);
                    ls[reg] += p;
                    pw[(m * 16 + r0 + reg) * ALD + nt * 16 + col0] = f2bf_rn(p);
                }
            #pragma unroll
            for (int off = 1; off < 16; off <<= 1)
                #pragma unroll
                for (int reg = 0; reg < 4; reg++)
                    ls[reg] += __shfl_xor(ls[reg], off, 64);
            #pragma unroll
            for (int reg = 0; reg < 4; reg++) l_i[m][reg] = l_i[m][reg] * alpha[reg] + ls[reg];
            #pragma unroll
            for (int nt = 0; nt < 4; nt++)
                #pragma unroll
                for (int reg = 0; reg < 4; reg++) Oacc[m][nt][reg] *= alpha[reg];
        }

        // PV: load P frags for active bands, then stream V frags once
        bf16x8 p0[2], p1[2];
        #pragma unroll
        for (int m = 0; m < 2; m++) {
            if (m == 0 && skip0) continue;
            p0[m] = *reinterpret_cast<const bf16x8*>(&pw[(m * 16 + mrow) * ALD + koff]);
            p1[m] = *reinterpret_cast<const bf16x8*>(&pw[(m * 16 + mrow) * ALD + 32 + koff]);
        }
        #pragma unroll
        for (int nt = 0; nt < 4; nt++) {
            const bf16x8 v0 = *reinterpret_cast<const bf16x8*>(&vs[(nt * 16 + mrow) * ALD + koff]);
            const bf16x8 v1 = *reinterpret_cast<const bf16x8*>(&vs[(nt * 16 + mrow) * ALD + 32 + koff]);
            #pragma unroll
            for (int m = 0; m < 2; m++) {
                if (m == 0 && skip0) continue;
                Oacc[m][nt] = __builtin_amdgcn_mfma_f32_16x16x32_bf16(p0[m], v0, Oacc[m][nt], 0, 0, 0);
                Oacc[m][nt] = __builtin_amdgcn_mfma_f32_16x16x32_bf16(p1[m], v1, Oacc[m][nt], 0, 0, 0);
            }
        }
    }

    #pragma unroll
    for (int m = 0; m < 2; m++) {
        float rl[4];
        #pragma unroll
        for (int reg = 0; reg < 4; reg++) rl[reg] = 1.f / l_i[m][reg];
        #pragma unroll
        for (int nt = 0; nt < 4; nt++)
            #pragma unroll
            for (int reg = 0; reg < 4; reg++) {
                const int q = qbase[m] + r0 + reg;
                const int d = nt * 16 + col0;
                ctx[((size_t)b * S_ + q) * H_ + h * HD_ + d] = f2bf_rn(Oacc[m][nt][reg] * rl[reg]);
            }
    }
}

// ---------------------------------------------------------------- launch
extern "C" void kernel_launch(void* const* d_in, const int* in_sizes, int n_in,
                              void* d_out, int out_size, void* d_ws, size_t ws_size,
                              hipStream_t stream) {
    const float* x     = (const float*)d_in[0];
    const int*   mask  = (const int*)d_in[1];
    const float* normw = (const float*)d_in[2];
    const float* normb = (const float*)d_in[3];
    const float* qkvw  = (const float*)d_in[4];
    const float* qkvb  = (const float*)d_in[5];
    const float* ow    = (const float*)d_in[6];
    const float* ob    = (const float*)d_in[7];
    float* out = (float*)d_out;

    char* ws = (char*)d_ws;
    unsigned short* xn_bf   = (unsigned short*)(ws);                      //  8 MB
    unsigned short* qkvwT   = (unsigned short*)(ws + (8ull  << 20));      //  6 MB
    unsigned short* owT     = (unsigned short*)(ws + (14ull << 20));      //  2 MB
    unsigned short* qkv_bf  = (unsigned short*)(ws + (16ull << 20));      // 24 MB
    unsigned short* Qb      = (unsigned short*)(ws + (40ull << 20));      //  8 MB [bh][s][d]
    unsigned short* Kb      = (unsigned short*)(ws + (48ull << 20));      //  8 MB [bh][s][d]
    unsigned short* Vtb     = (unsigned short*)(ws + (56ull << 20));      //  8 MB [bh][d][s]
    unsigned short* ctx_bf  = (unsigned short*)(ws + (64ull << 20));      //  8 MB

    cvt_transpose_k<<<dim3(H3_ / 64, H_ / 64), 256, 0, stream>>>(qkvw, qkvwT, H_, H3_);
    cvt_transpose_k<<<dim3(H_  / 64, H_ / 64), 256, 0, stream>>>(ow,   owT,   H_, H_);
    layernorm_k<<<T_, 256, 0, stream>>>(x, normw, normb, xn_bf);
    gemm_bf16<false><<<dim3(H3_ / BN, T_ / BM), 256, 0, stream>>>(xn_bf, qkvwT, qkvb,
                                                                  nullptr, qkv_bf, T_, H3_, H_);
    rotary_qk_k<<<T_, 256, 0, stream>>>(qkv_bf, Qb, Kb);
    v_transpose_k<<<dim3(S_ / 64, B_), 256, 0, stream>>>(qkv_bf, Vtb);
    attn_k<<<512, 256, 0, stream>>>(Qb, Kb, Vtb, mask, ctx_bf);
    gemm_bf16<true><<<dim3(H_ / BN, T_ / BM), 256, 0, stream>>>(ctx_bf, owT, ob,
                                                                out, nullptr, T_, H_, H_);
}

// Round 4
// 256.499 us; speedup vs baseline: 1.4579x; 1.4579x over previous
//
#include <hip/hip_runtime.h>
#include <hip/hip_bf16.h>

#define B_  2
#define S_  2048
#define H_  1024
#define NH_ 16
#define HD_ 64
#define T_  (B_*S_)     // 4096 tokens
#define H3_ (3*H_)      // 3072

typedef float  floatx4 __attribute__((ext_vector_type(4)));
typedef __bf16 bf16x8  __attribute__((ext_vector_type(8)));

__device__ inline unsigned short f2bf_rn(float f) {
    union { float f; unsigned int u; } v; v.f = f;
    unsigned int u = v.u;
    u += 0x7fffu + ((u >> 16) & 1u);
    return (unsigned short)(u >> 16);
}
__device__ inline floatx4 fzero4() { floatx4 v; v[0]=0.f; v[1]=0.f; v[2]=0.f; v[3]=0.f; return v; }

// async global->LDS, 16B per lane; LDS dest = wave-uniform base + lane*16
__device__ inline void gload_lds16(const unsigned short* g, unsigned short* l) {
    __builtin_amdgcn_global_load_lds((const __attribute__((address_space(1))) unsigned int*)g,
                                     (__attribute__((address_space(3))) unsigned int*)l,
                                     16, 0, 0);
}

// ---------------------------------------------------------------- fused cast + transpose: W[K][N] f32 -> Wt[N][K] bf16
#define TLD 72
__global__ __launch_bounds__(256) void cvt_transpose_k(const float* __restrict__ W,
                                                       unsigned short* __restrict__ Wt,
                                                       int K, int N) {
    __shared__ unsigned short Ts[64 * TLD];
    const int nb = blockIdx.x * 64;
    const int kb = blockIdx.y * 64;
    const int tid = threadIdx.x;
    #pragma unroll
    for (int p = 0; p < 4; p++) {
        const int krow = kb + p * 16 + (tid >> 4);
        const int ncol = (tid & 15) * 4;
        const float4 w = *reinterpret_cast<const float4*>(&W[(size_t)krow * N + nb + ncol]);
        Ts[(ncol + 0) * TLD + p * 16 + (tid >> 4)] = f2bf_rn(w.x);
        Ts[(ncol + 1) * TLD + p * 16 + (tid >> 4)] = f2bf_rn(w.y);
        Ts[(ncol + 2) * TLD + p * 16 + (tid >> 4)] = f2bf_rn(w.z);
        Ts[(ncol + 3) * TLD + p * 16 + (tid >> 4)] = f2bf_rn(w.w);
    }
    __syncthreads();
    #pragma unroll
    for (int p = 0; p < 2; p++) {
        const int n = (tid >> 3) + p * 32;
        const int k8 = (tid & 7) * 8;
        const uint4 v = *reinterpret_cast<const uint4*>(&Ts[n * TLD + k8]);
        *reinterpret_cast<uint4*>(&Wt[(size_t)(nb + n) * K + kb + k8]) = v;
    }
}

// ---------------------------------------------------------------- LayerNorm (fp32 stats, bf16 out)
__global__ __launch_bounds__(256) void layernorm_k(const float* __restrict__ x,
                                                   const float* __restrict__ w,
                                                   const float* __restrict__ b,
                                                   unsigned short* __restrict__ xn) {
    const int t   = blockIdx.x;
    const int tid = threadIdx.x;
    const float4 v = reinterpret_cast<const float4*>(x + (size_t)t * H_)[tid];
    float s  = v.x + v.y + v.z + v.w;
    float s2 = v.x*v.x + v.y*v.y + v.z*v.z + v.w*v.w;
    for (int off = 32; off > 0; off >>= 1) {
        s  += __shfl_down(s,  off, 64);
        s2 += __shfl_down(s2, off, 64);
    }
    __shared__ float red[8];
    const int wave = tid >> 6, lane = tid & 63;
    if (lane == 0) { red[wave] = s; red[4 + wave] = s2; }
    __syncthreads();
    if (tid == 0) {
        red[0] = red[0] + red[1] + red[2] + red[3];
        red[4] = red[4] + red[5] + red[6] + red[7];
    }
    __syncthreads();
    const float mean = red[0] * (1.f / H_);
    const float var  = red[4] * (1.f / H_) - mean * mean;
    const float rstd = rsqrtf(var + 1e-5f);
    const float4 wv = reinterpret_cast<const float4*>(w)[tid];
    const float4 bv = reinterpret_cast<const float4*>(b)[tid];
    ushort4 o = make_ushort4(f2bf_rn((v.x - mean) * rstd * wv.x + bv.x),
                             f2bf_rn((v.y - mean) * rstd * wv.y + bv.y),
                             f2bf_rn((v.z - mean) * rstd * wv.z + bv.z),
                             f2bf_rn((v.w - mean) * rstd * wv.w + bv.w));
    reinterpret_cast<ushort4*>(xn + (size_t)t * H_)[tid] = o;
}

// ---------------------------------------------------------------- bf16 MFMA GEMM  C = A(MxK) @ Bt(NxK)^T + bias
// m97 recipe: 128x128 tile, BK=32, single-buffer unpadded LDS, global_load_lds width16, 2-barrier K-loop.
#define BM 128
#define BN 128
#define BK 32

template <bool OUT_F32>
__global__ __launch_bounds__(256) void gemm_bf16(const unsigned short* __restrict__ A,
                                                 const unsigned short* __restrict__ Bt,
                                                 const float* __restrict__ bias,
                                                 float* __restrict__ Cf,
                                                 unsigned short* __restrict__ Cb,
                                                 int M, int N, int K) {
    __shared__ unsigned short As[BM * BK];   // [m][k], 64B rows, unpadded (required by global_load_lds)
    __shared__ unsigned short Bs[BN * BK];   // [n][k]

    const int tid  = threadIdx.x;
    const int lane = tid & 63;
    const int wave = tid >> 6;
    const int wr = wave >> 1, wc = wave & 1;
    const int mBase = blockIdx.y * BM;
    const int nBase = blockIdx.x * BN;

    floatx4 acc[4][4];
    #pragma unroll
    for (int i = 0; i < 4; i++)
        #pragma unroll
        for (int j = 0; j < 4; j++) acc[i][j] = fzero4();

    const int srow = lane >> 2;        // 0..15 within wave's 16-row chunk
    const int scol = (lane & 3) * 8;   // 0,8,16,24
    const int mrow = lane & 15;
    const int koff = (lane >> 4) * 8;

    for (int kb = 0; kb < K; kb += BK) {
        __syncthreads();   // WAR: prior iteration's ds_reads done before overwrite
        #pragma unroll
        for (int p = 0; p < 2; p++) {
            const int r = wave * 16 + p * 64;                    // wave-uniform row base
            gload_lds16(&A [(size_t)(mBase + r + srow) * K + kb + scol], &As[r * BK]);
            gload_lds16(&Bt[(size_t)(nBase + r + srow) * K + kb + scol], &Bs[r * BK]);
        }
        __syncthreads();   // drains vmcnt -> staged tile visible

        bf16x8 afrag[4], bfrag[4];
        #pragma unroll
        for (int mt = 0; mt < 4; mt++)
            afrag[mt] = *reinterpret_cast<const bf16x8*>(&As[(wr * 64 + mt * 16 + mrow) * BK + koff]);
        #pragma unroll
        for (int nt = 0; nt < 4; nt++)
            bfrag[nt] = *reinterpret_cast<const bf16x8*>(&Bs[(wc * 64 + nt * 16 + mrow) * BK + koff]);
        #pragma unroll
        for (int mt = 0; mt < 4; mt++)
            #pragma unroll
            for (int nt = 0; nt < 4; nt++)
                acc[mt][nt] = __builtin_amdgcn_mfma_f32_16x16x32_bf16(afrag[mt], bfrag[nt], acc[mt][nt], 0, 0, 0);
    }

    const int col0 = lane & 15;
    const int r0   = (lane >> 4) * 4;
    #pragma unroll
    for (int mt = 0; mt < 4; mt++) {
        #pragma unroll
        for (int nt = 0; nt < 4; nt++) {
            const int gcol = nBase + wc * 64 + nt * 16 + col0;
            const float bs = bias[gcol];
            #pragma unroll
            for (int reg = 0; reg < 4; reg++) {
                const int grow = mBase + wr * 64 + mt * 16 + r0 + reg;
                const float v = acc[mt][nt][reg] + bs;
                if constexpr (OUT_F32) Cf[(size_t)grow * N + gcol] = v;
                else                   Cb[(size_t)grow * N + gcol] = f2bf_rn(v);
            }
        }
    }
}

// ---------------------------------------------------------------- rotary for q,k -> Q/K [b,h,s,d] bf16
__global__ __launch_bounds__(256) void rotary_qk_k(const unsigned short* __restrict__ qkv,
                                                   unsigned short* __restrict__ Q,
                                                   unsigned short* __restrict__ K) {
    const int t   = blockIdx.x;
    const int b   = t / S_;
    const int s   = t % S_;
    const int tid = threadIdx.x;
    const unsigned short* row = qkv + (size_t)t * H3_;
    #pragma unroll
    for (int i = 0; i < 4; i++) {
        const int idx = tid + i * 256;    // h*64 + d
        const int h = idx >> 6, d = idx & 63;
        const float inv_freq = __expf((float)(d & 31) * (-0.2878231366f)); // -ln(10000)/32
        const float fr = (float)s * inv_freq;
        float sn, cs;
        __sincosf(fr, &sn, &cs);
        const size_t dst = ((size_t)(b * NH_ + h) * S_ + s) * HD_ + d;
        {
            union { unsigned int u; float f; } a, p;
            a.u = ((unsigned int)row[idx]) << 16;
            p.u = ((unsigned int)row[idx ^ 32]) << 16;
            const float rot = (d < 32) ? -p.f : p.f;
            Q[dst] = f2bf_rn(a.f * cs + rot * sn);
        }
        {
            union { unsigned int u; float f; } a, p;
            a.u = ((unsigned int)row[H_ + idx]) << 16;
            p.u = ((unsigned int)row[H_ + (idx ^ 32)]) << 16;
            const float rot = (d < 32) ? -p.f : p.f;
            K[dst] = f2bf_rn(a.f * cs + rot * sn);
        }
    }
}

// ---------------------------------------------------------------- V transpose: qkv v-part -> Vt[bh][d][s]
__global__ __launch_bounds__(256) void v_transpose_k(const unsigned short* __restrict__ qkv,
                                                     unsigned short* __restrict__ Vt) {
    __shared__ unsigned short Vs[64 * TLD];
    const int s0 = blockIdx.x * 64;
    const int b  = blockIdx.y;
    const int tid = threadIdx.x;
    for (int h = 0; h < NH_; h++) {
        __syncthreads();
        #pragma unroll
        for (int p = 0; p < 2; p++) {
            const int tl = tid >> 2;
            const int c  = (tid & 3) * 8 + p * 32;
            const uint4 v = *reinterpret_cast<const uint4*>(
                &qkv[(size_t)(b * S_ + s0 + tl) * H3_ + 2 * H_ + h * 64 + c]);
            *reinterpret_cast<uint4*>(&Vs[tl * TLD + c]) = v;
        }
        __syncthreads();
        #pragma unroll
        for (int p = 0; p < 2; p++) {
            const int d  = (tid >> 3) + p * 32;
            const int s8 = (tid & 7) * 8;
            unsigned short tmp[8];
            #pragma unroll
            for (int jj = 0; jj < 8; jj++) tmp[jj] = Vs[(s8 + jj) * TLD + d];
            *reinterpret_cast<uint4*>(&Vt[((size_t)(b * NH_ + h) * HD_ + d) * S_ + s0 + s8]) =
                *reinterpret_cast<uint4*>(tmp);
        }
    }
}

// ---------------------------------------------------------------- flash attention, band-paired, ping-pong LDS
#define ALD 72

__global__ __launch_bounds__(256, 2) void attn_k(const unsigned short* __restrict__ Q,
                                                 const unsigned short* __restrict__ Kg,
                                                 const unsigned short* __restrict__ Vt,
                                                 const int* __restrict__ mask,
                                                 unsigned short* __restrict__ ctx) {
    // XCD swizzle: all 16 j-blocks of a head share id%8 -> same XCD (round-robin heuristic)
    const int id = blockIdx.x;              // 0..511
    const int bh = (id & 7) + 8 * (id >> 7);
    const int j  = (id >> 3) & 15;
    const int b  = bh >> 4;
    const int h  = bh & 15;
    const int tid  = threadIdx.x;
    const int lane = tid & 63;
    const int wave = tid >> 6;

    __shared__ unsigned short Ks [2][64 * ALD];
    __shared__ unsigned short Vts[2][64 * ALD];
    __shared__ unsigned short Ps[4][32 * ALD];

    const size_t base = (size_t)bh * S_ * HD_;
    const int qbase[2] = { j * 64 + wave * 16, (31 - j) * 64 + wave * 16 };
    const int mrow = lane & 15;
    const int koff = (lane >> 4) * 8;
    const int r0   = (lane >> 4) * 4;
    const int col0 = lane & 15;

    bf16x8 qf[2][2];
    #pragma unroll
    for (int m = 0; m < 2; m++)
        #pragma unroll
        for (int hh = 0; hh < 2; hh++)
            qf[m][hh] = *reinterpret_cast<const bf16x8*>(
                &Q[base + (size_t)(qbase[m] + mrow) * HD_ + hh * 32 + koff]);

    floatx4 Oacc[2][4];
    float m_i[2][4], l_i[2][4];
    #pragma unroll
    for (int m = 0; m < 2; m++) {
        #pragma unroll
        for (int nt = 0; nt < 4; nt++) Oacc[m][nt] = fzero4();
        #pragma unroll
        for (int r = 0; r < 4; r++) { m_i[m][r] = -1e30f; l_i[m][r] = 0.f; }
    }

    const int last = 31 - j;
    const int srow = tid >> 3;          // 0..31
    const int scol = (tid & 7) * 8;

    // named prefetch registers (NO lambda / arrays: avoids scratch alloca)
    uint4 kreg0, kreg1, vreg0, vreg1;
    float mb0, mb1, mb2, mb3;
#define PREFETCH(KT) do {                                                                      \
        const int kb_ = (KT) * 64;                                                             \
        kreg0 = *reinterpret_cast<const uint4*>(&Kg[base + (size_t)(kb_ + srow)      * HD_ + scol]); \
        kreg1 = *reinterpret_cast<const uint4*>(&Kg[base + (size_t)(kb_ + srow + 32) * HD_ + scol]); \
        vreg0 = *reinterpret_cast<const uint4*>(&Vt[base + (size_t)srow        * S_ + kb_ + scol]);  \
        vreg1 = *reinterpret_cast<const uint4*>(&Vt[base + (size_t)(srow + 32) * S_ + kb_ + scol]);  \
        mb0 = (1.f - (float)mask[b * S_ + kb_ +  0 + col0]) * (-10000.f);                      \
        mb1 = (1.f - (float)mask[b * S_ + kb_ + 16 + col0]) * (-10000.f);                      \
        mb2 = (1.f - (float)mask[b * S_ + kb_ + 32 + col0]) * (-10000.f);                      \
        mb3 = (1.f - (float)mask[b * S_ + kb_ + 48 + col0]) * (-10000.f);                      \
    } while (0)

    PREFETCH(0);

    for (int kt = 0; kt <= last; kt++) {
        const int kb  = kt * 64;
        const int buf = kt & 1;
        unsigned short* ks = Ks [buf];
        unsigned short* vs = Vts[buf];
        *reinterpret_cast<uint4*>(&ks[ srow       * ALD + scol]) = kreg0;
        *reinterpret_cast<uint4*>(&ks[(srow + 32) * ALD + scol]) = kreg1;
        *reinterpret_cast<uint4*>(&vs[ srow       * ALD + scol]) = vreg0;
        *reinterpret_cast<uint4*>(&vs[(srow + 32) * ALD + scol]) = vreg1;
        __syncthreads();
        const float mc0 = mb0, mc1 = mb1, mc2 = mb2, mc3 = mb3;
        if (kt < last) PREFETCH(kt + 1);

        const bool skip0 = (kt > j);
        unsigned short* pw = Ps[wave];

        #pragma unroll
        for (int m = 0; m < 2; m++) {
            if (m == 0 && skip0) continue;
            floatx4 sc[4];
            #pragma unroll
            for (int nt = 0; nt < 4; nt++) {
                const bf16x8 k0 = *reinterpret_cast<const bf16x8*>(&ks[(nt * 16 + mrow) * ALD + koff]);
                const bf16x8 k1 = *reinterpret_cast<const bf16x8*>(&ks[(nt * 16 + mrow) * ALD + 32 + koff]);
                floatx4 c = fzero4();
                c = __builtin_amdgcn_mfma_f32_16x16x32_bf16(qf[m][0], k0, c, 0, 0, 0);
                c = __builtin_amdgcn_mfma_f32_16x16x32_bf16(qf[m][1], k1, c, 0, 0, 0);
                sc[nt] = c;
            }
            const bool needc = (kb + 63) > qbase[m];
            float mt[4];
            #pragma unroll
            for (int r = 0; r < 4; r++) mt[r] = -1e30f;
            #pragma unroll
            for (int nt = 0; nt < 4; nt++) {
                const float mbv = (nt == 0) ? mc0 : (nt == 1) ? mc1 : (nt == 2) ? mc2 : mc3;
                #pragma unroll
                for (int reg = 0; reg < 4; reg++) {
                    float sv = sc[nt][reg] * 0.125f + mbv;
                    if (needc) {
                        const int key = kb + nt * 16 + col0;
                        const int q   = qbase[m] + r0 + reg;
                        if (key > q) sv = -10000.f;
                    }
                    sc[nt][reg] = sv;
                    mt[reg] = fmaxf(mt[reg], sv);
                }
            }
            #pragma unroll
            for (int off = 1; off < 16; off <<= 1)
                #pragma unroll
                for (int reg = 0; reg < 4; reg++)
                    mt[reg] = fmaxf(mt[reg], __shfl_xor(mt[reg], off, 64));
            float alpha[4], ls[4];
            #pragma unroll
            for (int reg = 0; reg < 4; reg++) {
                const float mn = fmaxf(m_i[m][reg], mt[reg]);
                alpha[reg] = __expf(m_i[m][reg] - mn);
                m_i[m][reg] = mn;
                ls[reg] = 0.f;
            }
            #pragma unroll
            for (int nt = 0; nt < 4; nt++)
                #pragma unroll
                for (int reg = 0; reg < 4; reg++) {
                    const float p = __expf(sc[nt][reg] - m_i[m][reg]);
                    ls[reg] += p;
                    pw[(m * 16 + r0 + reg) * ALD + nt * 16 + col0] = f2bf_rn(p);
                }
            #pragma unroll
            for (int off = 1; off < 16; off <<= 1)
                #pragma unroll
                for (int reg = 0; reg < 4; reg++)
                    ls[reg] += __shfl_xor(ls[reg], off, 64);
            #pragma unroll
            for (int reg = 0; reg < 4; reg++) l_i[m][reg] = l_i[m][reg] * alpha[reg] + ls[reg];
            #pragma unroll
            for (int nt = 0; nt < 4; nt++)
                #pragma unroll
                for (int reg = 0; reg < 4; reg++) Oacc[m][nt][reg] *= alpha[reg];
        }

        // PV: load P frags for active bands, then stream V frags once
        bf16x8 p0[2], p1[2];
        #pragma unroll
        for (int m = 0; m < 2; m++) {
            if (m == 0 && skip0) continue;
            p0[m] = *reinterpret_cast<const bf16x8*>(&pw[(m * 16 + mrow) * ALD + koff]);
            p1[m] = *reinterpret_cast<const bf16x8*>(&pw[(m * 16 + mrow) * ALD + 32 + koff]);
        }
        #pragma unroll
        for (int nt = 0; nt < 4; nt++) {
            const bf16x8 v0 = *reinterpret_cast<const bf16x8*>(&vs[(nt * 16 + mrow) * ALD + koff]);
            const bf16x8 v1 = *reinterpret_cast<const bf16x8*>(&vs[(nt * 16 + mrow) * ALD + 32 + koff]);
            #pragma unroll
            for (int m = 0; m < 2; m++) {
                if (m == 0 && skip0) continue;
                Oacc[m][nt] = __builtin_amdgcn_mfma_f32_16x16x32_bf16(p0[m], v0, Oacc[m][nt], 0, 0, 0);
                Oacc[m][nt] = __builtin_amdgcn_mfma_f32_16x16x32_bf16(p1[m], v1, Oacc[m][nt], 0, 0, 0);
            }
        }
    }
#undef PREFETCH

    #pragma unroll
    for (int m = 0; m < 2; m++) {
        float rl[4];
        #pragma unroll
        for (int reg = 0; reg < 4; reg++) rl[reg] = 1.f / l_i[m][reg];
        #pragma unroll
        for (int nt = 0; nt < 4; nt++)
            #pragma unroll
            for (int reg = 0; reg < 4; reg++) {
                const int q = qbase[m] + r0 + reg;
                const int d = nt * 16 + col0;
                ctx[((size_t)b * S_ + q) * H_ + h * HD_ + d] = f2bf_rn(Oacc[m][nt][reg] * rl[reg]);
            }
    }
}

// ---------------------------------------------------------------- launch
extern "C" void kernel_launch(void* const* d_in, const int* in_sizes, int n_in,
                              void* d_out, int out_size, void* d_ws, size_t ws_size,
                              hipStream_t stream) {
    const float* x     = (const float*)d_in[0];
    const int*   mask  = (const int*)d_in[1];
    const float* normw = (const float*)d_in[2];
    const float* normb = (const float*)d_in[3];
    const float* qkvw  = (const float*)d_in[4];
    const float* qkvb  = (const float*)d_in[5];
    const float* ow    = (const float*)d_in[6];
    const float* ob    = (const float*)d_in[7];
    float* out = (float*)d_out;

    char* ws = (char*)d_ws;
    unsigned short* xn_bf   = (unsigned short*)(ws);                      //  8 MB
    unsigned short* qkvwT   = (unsigned short*)(ws + (8ull  << 20));      //  6 MB
    unsigned short* owT     = (unsigned short*)(ws + (14ull << 20));      //  2 MB
    unsigned short* qkv_bf  = (unsigned short*)(ws + (16ull << 20));      // 24 MB
    unsigned short* Qb      = (unsigned short*)(ws + (40ull << 20));      //  8 MB [bh][s][d]
    unsigned short* Kb      = (unsigned short*)(ws + (48ull << 20));      //  8 MB [bh][s][d]
    unsigned short* Vtb     = (unsigned short*)(ws + (56ull << 20));      //  8 MB [bh][d][s]
    unsigned short* ctx_bf  = (unsigned short*)(ws + (64ull << 20));      //  8 MB

    cvt_transpose_k<<<dim3(H3_ / 64, H_ / 64), 256, 0, stream>>>(qkvw, qkvwT, H_, H3_);
    cvt_transpose_k<<<dim3(H_  / 64, H_ / 64), 256, 0, stream>>>(ow,   owT,   H_, H_);
    layernorm_k<<<T_, 256, 0, stream>>>(x, normw, normb, xn_bf);
    gemm_bf16<false><<<dim3(H3_ / BN, T_ / BM), 256, 0, stream>>>(xn_bf, qkvwT, qkvb,
                                                                  nullptr, qkv_bf, T_, H3_, H_);
    rotary_qk_k<<<T_, 256, 0, stream>>>(qkv_bf, Qb, Kb);
    v_transpose_k<<<dim3(S_ / 64, B_), 256, 0, stream>>>(qkv_bf, Vtb);
    attn_k<<<512, 256, 0, stream>>>(Qb, Kb, Vtb, mask, ctx_bf);
    gemm_bf16<true><<<dim3(H_ / BN, T_ / BM), 256, 0, stream>>>(ctx_bf, owT, ob,
                                                                out, nullptr, T_, H_, H_);
}

// Round 5
// 252.239 us; speedup vs baseline: 1.4825x; 1.0169x over previous
//
#include <hip/hip_runtime.h>
#include <hip/hip_bf16.h>

#define B_  2
#define S_  2048
#define H_  1024
#define NH_ 16
#define HD_ 64
#define T_  (B_*S_)     // 4096 tokens
#define H3_ (3*H_)      // 3072

typedef float  floatx4 __attribute__((ext_vector_type(4)));
typedef __bf16 bf16x8  __attribute__((ext_vector_type(8)));

__device__ inline unsigned short f2bf_rn(float f) {
    union { float f; unsigned int u; } v; v.f = f;
    unsigned int u = v.u;
    u += 0x7fffu + ((u >> 16) & 1u);
    return (unsigned short)(u >> 16);
}
__device__ inline unsigned short f2bf_tr(float f) {   // truncate (1 op) — self-consistent w/ MFMA-summed l
    union { float f; unsigned int u; } v; v.f = f;
    return (unsigned short)(v.u >> 16);
}
__device__ inline floatx4 fzero4() { floatx4 v; v[0]=0.f; v[1]=0.f; v[2]=0.f; v[3]=0.f; return v; }

// async global->LDS, 16B per lane; LDS dest = wave-uniform base + lane*16
__device__ inline void gload_lds16(const unsigned short* g, unsigned short* l) {
    __builtin_amdgcn_global_load_lds((const __attribute__((address_space(1))) unsigned int*)g,
                                     (__attribute__((address_space(3))) unsigned int*)l,
                                     16, 0, 0);
}

// ---------------------------------------------------------------- fused cast + transpose: W[K][N] f32 -> Wt[N][K] bf16
#define TLD 72
__global__ __launch_bounds__(256) void cvt_transpose_k(const float* __restrict__ W,
                                                       unsigned short* __restrict__ Wt,
                                                       int K, int N) {
    __shared__ unsigned short Ts[64 * TLD];
    const int nb = blockIdx.x * 64;
    const int kb = blockIdx.y * 64;
    const int tid = threadIdx.x;
    #pragma unroll
    for (int p = 0; p < 4; p++) {
        const int krow = kb + p * 16 + (tid >> 4);
        const int ncol = (tid & 15) * 4;
        const float4 w = *reinterpret_cast<const float4*>(&W[(size_t)krow * N + nb + ncol]);
        Ts[(ncol + 0) * TLD + p * 16 + (tid >> 4)] = f2bf_rn(w.x);
        Ts[(ncol + 1) * TLD + p * 16 + (tid >> 4)] = f2bf_rn(w.y);
        Ts[(ncol + 2) * TLD + p * 16 + (tid >> 4)] = f2bf_rn(w.z);
        Ts[(ncol + 3) * TLD + p * 16 + (tid >> 4)] = f2bf_rn(w.w);
    }
    __syncthreads();
    #pragma unroll
    for (int p = 0; p < 2; p++) {
        const int n = (tid >> 3) + p * 32;
        const int k8 = (tid & 7) * 8;
        const uint4 v = *reinterpret_cast<const uint4*>(&Ts[n * TLD + k8]);
        *reinterpret_cast<uint4*>(&Wt[(size_t)(nb + n) * K + kb + k8]) = v;
    }
}

// ---------------------------------------------------------------- LayerNorm (fp32 stats, bf16 out)
__global__ __launch_bounds__(256) void layernorm_k(const float* __restrict__ x,
                                                   const float* __restrict__ w,
                                                   const float* __restrict__ b,
                                                   unsigned short* __restrict__ xn) {
    const int t   = blockIdx.x;
    const int tid = threadIdx.x;
    const float4 v = reinterpret_cast<const float4*>(x + (size_t)t * H_)[tid];
    float s  = v.x + v.y + v.z + v.w;
    float s2 = v.x*v.x + v.y*v.y + v.z*v.z + v.w*v.w;
    for (int off = 32; off > 0; off >>= 1) {
        s  += __shfl_down(s,  off, 64);
        s2 += __shfl_down(s2, off, 64);
    }
    __shared__ float red[8];
    const int wave = tid >> 6, lane = tid & 63;
    if (lane == 0) { red[wave] = s; red[4 + wave] = s2; }
    __syncthreads();
    if (tid == 0) {
        red[0] = red[0] + red[1] + red[2] + red[3];
        red[4] = red[4] + red[5] + red[6] + red[7];
    }
    __syncthreads();
    const float mean = red[0] * (1.f / H_);
    const float var  = red[4] * (1.f / H_) - mean * mean;
    const float rstd = rsqrtf(var + 1e-5f);
    const float4 wv = reinterpret_cast<const float4*>(w)[tid];
    const float4 bv = reinterpret_cast<const float4*>(b)[tid];
    ushort4 o = make_ushort4(f2bf_rn((v.x - mean) * rstd * wv.x + bv.x),
                             f2bf_rn((v.y - mean) * rstd * wv.y + bv.y),
                             f2bf_rn((v.z - mean) * rstd * wv.z + bv.z),
                             f2bf_rn((v.w - mean) * rstd * wv.w + bv.w));
    reinterpret_cast<ushort4*>(xn + (size_t)t * H_)[tid] = o;
}

// ---------------------------------------------------------------- bf16 MFMA GEMM  C = A(MxK) @ Bt(NxK)^T + bias
// m97 recipe: 128x128 tile, BK=32, single-buffer unpadded LDS, global_load_lds width16, 2-barrier K-loop.
#define BM 128
#define BN 128
#define BK 32

template <bool OUT_F32>
__global__ __launch_bounds__(256) void gemm_bf16(const unsigned short* __restrict__ A,
                                                 const unsigned short* __restrict__ Bt,
                                                 const float* __restrict__ bias,
                                                 float* __restrict__ Cf,
                                                 unsigned short* __restrict__ Cb,
                                                 int M, int N, int K) {
    __shared__ unsigned short As[BM * BK];
    __shared__ unsigned short Bs[BN * BK];

    const int tid  = threadIdx.x;
    const int lane = tid & 63;
    const int wave = tid >> 6;
    const int wr = wave >> 1, wc = wave & 1;
    const int mBase = blockIdx.y * BM;
    const int nBase = blockIdx.x * BN;

    floatx4 acc[4][4];
    #pragma unroll
    for (int i = 0; i < 4; i++)
        #pragma unroll
        for (int j = 0; j < 4; j++) acc[i][j] = fzero4();

    const int srow = lane >> 2;
    const int scol = (lane & 3) * 8;
    const int mrow = lane & 15;
    const int koff = (lane >> 4) * 8;

    for (int kb = 0; kb < K; kb += BK) {
        __syncthreads();
        #pragma unroll
        for (int p = 0; p < 2; p++) {
            const int r = wave * 16 + p * 64;
            gload_lds16(&A [(size_t)(mBase + r + srow) * K + kb + scol], &As[r * BK]);
            gload_lds16(&Bt[(size_t)(nBase + r + srow) * K + kb + scol], &Bs[r * BK]);
        }
        __syncthreads();

        bf16x8 afrag[4], bfrag[4];
        #pragma unroll
        for (int mt = 0; mt < 4; mt++)
            afrag[mt] = *reinterpret_cast<const bf16x8*>(&As[(wr * 64 + mt * 16 + mrow) * BK + koff]);
        #pragma unroll
        for (int nt = 0; nt < 4; nt++)
            bfrag[nt] = *reinterpret_cast<const bf16x8*>(&Bs[(wc * 64 + nt * 16 + mrow) * BK + koff]);
        #pragma unroll
        for (int mt = 0; mt < 4; mt++)
            #pragma unroll
            for (int nt = 0; nt < 4; nt++)
                acc[mt][nt] = __builtin_amdgcn_mfma_f32_16x16x32_bf16(afrag[mt], bfrag[nt], acc[mt][nt], 0, 0, 0);
    }

    const int col0 = lane & 15;
    const int r0   = (lane >> 4) * 4;
    #pragma unroll
    for (int mt = 0; mt < 4; mt++) {
        #pragma unroll
        for (int nt = 0; nt < 4; nt++) {
            const int gcol = nBase + wc * 64 + nt * 16 + col0;
            const float bs = bias[gcol];
            #pragma unroll
            for (int reg = 0; reg < 4; reg++) {
                const int grow = mBase + wr * 64 + mt * 16 + r0 + reg;
                const float v = acc[mt][nt][reg] + bs;
                if constexpr (OUT_F32) Cf[(size_t)grow * N + gcol] = v;
                else                   Cb[(size_t)grow * N + gcol] = f2bf_rn(v);
            }
        }
    }
}

// ---------------------------------------------------------------- rotary for q,k -> Q/K [b,h,s,d] bf16
__global__ __launch_bounds__(256) void rotary_qk_k(const unsigned short* __restrict__ qkv,
                                                   unsigned short* __restrict__ Q,
                                                   unsigned short* __restrict__ K) {
    const int t   = blockIdx.x;
    const int b   = t / S_;
    const int s   = t % S_;
    const int tid = threadIdx.x;
    const unsigned short* row = qkv + (size_t)t * H3_;
    #pragma unroll
    for (int i = 0; i < 4; i++) {
        const int idx = tid + i * 256;    // h*64 + d
        const int h = idx >> 6, d = idx & 63;
        const float inv_freq = __expf((float)(d & 31) * (-0.2878231366f)); // -ln(10000)/32
        const float fr = (float)s * inv_freq;
        float sn, cs;
        __sincosf(fr, &sn, &cs);
        const size_t dst = ((size_t)(b * NH_ + h) * S_ + s) * HD_ + d;
        {
            union { unsigned int u; float f; } a, p;
            a.u = ((unsigned int)row[idx]) << 16;
            p.u = ((unsigned int)row[idx ^ 32]) << 16;
            const float rot = (d < 32) ? -p.f : p.f;
            Q[dst] = f2bf_rn(a.f * cs + rot * sn);
        }
        {
            union { unsigned int u; float f; } a, p;
            a.u = ((unsigned int)row[H_ + idx]) << 16;
            p.u = ((unsigned int)row[H_ + (idx ^ 32)]) << 16;
            const float rot = (d < 32) ? -p.f : p.f;
            K[dst] = f2bf_rn(a.f * cs + rot * sn);
        }
    }
}

// ---------------------------------------------------------------- V transpose: qkv v-part -> Vt[bh][d][s]
__global__ __launch_bounds__(256) void v_transpose_k(const unsigned short* __restrict__ qkv,
                                                     unsigned short* __restrict__ Vt) {
    __shared__ unsigned short Vs[64 * TLD];
    const int s0 = blockIdx.x * 64;
    const int b  = blockIdx.y;
    const int tid = threadIdx.x;
    for (int h = 0; h < NH_; h++) {
        __syncthreads();
        #pragma unroll
        for (int p = 0; p < 2; p++) {
            const int tl = tid >> 2;
            const int c  = (tid & 3) * 8 + p * 32;
            const uint4 v = *reinterpret_cast<const uint4*>(
                &qkv[(size_t)(b * S_ + s0 + tl) * H3_ + 2 * H_ + h * 64 + c]);
            *reinterpret_cast<uint4*>(&Vs[tl * TLD + c]) = v;
        }
        __syncthreads();
        #pragma unroll
        for (int p = 0; p < 2; p++) {
            const int d  = (tid >> 3) + p * 32;
            const int s8 = (tid & 7) * 8;
            unsigned short tmp[8];
            #pragma unroll
            for (int jj = 0; jj < 8; jj++) tmp[jj] = Vs[(s8 + jj) * TLD + d];
            *reinterpret_cast<uint4*>(&Vt[((size_t)(b * NH_ + h) * HD_ + d) * S_ + s0 + s8]) =
                *reinterpret_cast<uint4*>(tmp);
        }
    }
}

// ---------------------------------------------------------------- flash attention, band-paired, ping-pong LDS
// log2-domain softmax; l via MFMA ones-column; per-band PV (16-row Ps -> 46KB LDS, 3 blocks/CU)
#define ALD 72
#define SCL2 0.1803368801f      /* 0.125 * log2(e) */
#define MNEG -14427.0f          /* -10000 * log2(e), causal fill */

__global__ __launch_bounds__(256, 3) void attn_k(const unsigned short* __restrict__ Q,
                                                 const unsigned short* __restrict__ Kg,
                                                 const unsigned short* __restrict__ Vt,
                                                 const int* __restrict__ mask,
                                                 unsigned short* __restrict__ ctx) {
    const int id = blockIdx.x;              // 0..511
    const int bh = (id & 7) + 8 * (id >> 7);
    const int j  = (id >> 3) & 15;
    const int b  = bh >> 4;
    const int h  = bh & 15;
    const int tid  = threadIdx.x;
    const int lane = tid & 63;
    const int wave = tid >> 6;

    __shared__ unsigned short Ks [2][64 * ALD];   // 18.4 KB
    __shared__ unsigned short Vts[2][64 * ALD];   // 18.4 KB
    __shared__ unsigned short Ps[4][16 * ALD];    //  9.2 KB -> 46 KB total

    const size_t base = (size_t)bh * S_ * HD_;
    const int qbase[2] = { j * 64 + wave * 16, (31 - j) * 64 + wave * 16 };
    const int mrow = lane & 15;
    const int koff = (lane >> 4) * 8;
    const int r0   = (lane >> 4) * 4;
    const int col0 = lane & 15;

    bf16x8 qf[2][2];
    #pragma unroll
    for (int m = 0; m < 2; m++)
        #pragma unroll
        for (int hh = 0; hh < 2; hh++)
            qf[m][hh] = *reinterpret_cast<const bf16x8*>(
                &Q[base + (size_t)(qbase[m] + mrow) * HD_ + hh * 32 + koff]);

    // ones B-fragment: B[k][n] = (n==0); lanes with mrow==0 hold 1.0bf16
    bf16x8 onesf;
    {
        const __bf16 ov = (__bf16)((mrow == 0) ? 1.f : 0.f);
        #pragma unroll
        for (int q = 0; q < 8; q++) onesf[q] = ov;
    }

    floatx4 Oacc[2][4];   // output accumulators
    floatx4 Lacc[2];      // P @ ones -> denominator accumulator (col0 lanes)
    float m_i[2][4];
    #pragma unroll
    for (int m = 0; m < 2; m++) {
        #pragma unroll
        for (int nt = 0; nt < 4; nt++) Oacc[m][nt] = fzero4();
        Lacc[m] = fzero4();
        #pragma unroll
        for (int r = 0; r < 4; r++) m_i[m][r] = -1e30f;
    }

    const int last = 31 - j;
    const int srow = tid >> 3;          // 0..31
    const int scol = (tid & 7) * 8;

    uint4 kreg0, kreg1, vreg0, vreg1;
    float mb0, mb1, mb2, mb3;
#define PREFETCH(KT) do {                                                                      \
        const int kb_ = (KT) * 64;                                                             \
        kreg0 = *reinterpret_cast<const uint4*>(&Kg[base + (size_t)(kb_ + srow)      * HD_ + scol]); \
        kreg1 = *reinterpret_cast<const uint4*>(&Kg[base + (size_t)(kb_ + srow + 32) * HD_ + scol]); \
        vreg0 = *reinterpret_cast<const uint4*>(&Vt[base + (size_t)srow        * S_ + kb_ + scol]);  \
        vreg1 = *reinterpret_cast<const uint4*>(&Vt[base + (size_t)(srow + 32) * S_ + kb_ + scol]);  \
        mb0 = (1.f - (float)mask[b * S_ + kb_ +  0 + col0]) * MNEG;                            \
        mb1 = (1.f - (float)mask[b * S_ + kb_ + 16 + col0]) * MNEG;                            \
        mb2 = (1.f - (float)mask[b * S_ + kb_ + 32 + col0]) * MNEG;                            \
        mb3 = (1.f - (float)mask[b * S_ + kb_ + 48 + col0]) * MNEG;                            \
    } while (0)

    PREFETCH(0);

    for (int kt = 0; kt <= last; kt++) {
        const int kb  = kt * 64;
        const int buf = kt & 1;
        unsigned short* ks = Ks [buf];
        unsigned short* vs = Vts[buf];
        *reinterpret_cast<uint4*>(&ks[ srow       * ALD + scol]) = kreg0;
        *reinterpret_cast<uint4*>(&ks[(srow + 32) * ALD + scol]) = kreg1;
        *reinterpret_cast<uint4*>(&vs[ srow       * ALD + scol]) = vreg0;
        *reinterpret_cast<uint4*>(&vs[(srow + 32) * ALD + scol]) = vreg1;
        __syncthreads();
        const float mc0 = mb0, mc1 = mb1, mc2 = mb2, mc3 = mb3;
        if (kt < last) PREFETCH(kt + 1);

        const bool skip0 = (kt > j);
        unsigned short* pw = Ps[wave];

        #pragma unroll
        for (int m = 0; m < 2; m++) {
            if (m == 0 && skip0) continue;
            // ---- S = Q K^T
            floatx4 sc[4];
            #pragma unroll
            for (int nt = 0; nt < 4; nt++) {
                const bf16x8 k0 = *reinterpret_cast<const bf16x8*>(&ks[(nt * 16 + mrow) * ALD + koff]);
                const bf16x8 k1 = *reinterpret_cast<const bf16x8*>(&ks[(nt * 16 + mrow) * ALD + 32 + koff]);
                floatx4 c = fzero4();
                c = __builtin_amdgcn_mfma_f32_16x16x32_bf16(qf[m][0], k0, c, 0, 0, 0);
                c = __builtin_amdgcn_mfma_f32_16x16x32_bf16(qf[m][1], k1, c, 0, 0, 0);
                sc[nt] = c;
            }
            // ---- scale + bias (log2 domain)
            #pragma unroll
            for (int nt = 0; nt < 4; nt++) {
                const float mbv = (nt == 0) ? mc0 : (nt == 1) ? mc1 : (nt == 2) ? mc2 : mc3;
                #pragma unroll
                for (int reg = 0; reg < 4; reg++)
                    sc[nt][reg] = sc[nt][reg] * SCL2 + mbv;
            }
            // ---- causal (diagonal tiles only; wave-uniform branch)
            if ((kb + 63) > qbase[m]) {
                #pragma unroll
                for (int nt = 0; nt < 4; nt++) {
                    const int key = kb + nt * 16 + col0;
                    #pragma unroll
                    for (int reg = 0; reg < 4; reg++)
                        if (key > qbase[m] + r0 + reg) sc[nt][reg] = MNEG;
                }
            }
            // ---- row max (in-lane + 4 swizzle rounds)
            float mt[4];
            #pragma unroll
            for (int reg = 0; reg < 4; reg++)
                mt[reg] = fmaxf(fmaxf(sc[0][reg], sc[1][reg]), fmaxf(sc[2][reg], sc[3][reg]));
            #pragma unroll
            for (int off = 1; off < 16; off <<= 1)
                #pragma unroll
                for (int reg = 0; reg < 4; reg++)
                    mt[reg] = fmaxf(mt[reg], __shfl_xor(mt[reg], off, 64));
            float alpha[4];
            #pragma unroll
            for (int reg = 0; reg < 4; reg++) {
                const float mn = fmaxf(m_i[m][reg], mt[reg]);
                alpha[reg] = exp2f(m_i[m][reg] - mn);
                m_i[m][reg] = mn;
            }
            // ---- P = exp2(s - m), truncate-store to LDS (A-layout rows)
            #pragma unroll
            for (int nt = 0; nt < 4; nt++)
                #pragma unroll
                for (int reg = 0; reg < 4; reg++)
                    pw[(r0 + reg) * ALD + nt * 16 + col0] = f2bf_tr(exp2f(sc[nt][reg] - m_i[m][reg]));
            // ---- rescale accumulators
            #pragma unroll
            for (int nt = 0; nt < 4; nt++)
                #pragma unroll
                for (int reg = 0; reg < 4; reg++) Oacc[m][nt][reg] *= alpha[reg];
            #pragma unroll
            for (int reg = 0; reg < 4; reg++) Lacc[m][reg] *= alpha[reg];
            // ---- PV (+ ones-column for denominator)
            const bf16x8 p0 = *reinterpret_cast<const bf16x8*>(&pw[mrow * ALD + koff]);
            const bf16x8 p1 = *reinterpret_cast<const bf16x8*>(&pw[mrow * ALD + 32 + koff]);
            #pragma unroll
            for (int nt = 0; nt < 4; nt++) {
                const bf16x8 v0 = *reinterpret_cast<const bf16x8*>(&vs[(nt * 16 + mrow) * ALD + koff]);
                const bf16x8 v1 = *reinterpret_cast<const bf16x8*>(&vs[(nt * 16 + mrow) * ALD + 32 + koff]);
                Oacc[m][nt] = __builtin_amdgcn_mfma_f32_16x16x32_bf16(p0, v0, Oacc[m][nt], 0, 0, 0);
                Oacc[m][nt] = __builtin_amdgcn_mfma_f32_16x16x32_bf16(p1, v1, Oacc[m][nt], 0, 0, 0);
            }
            Lacc[m] = __builtin_amdgcn_mfma_f32_16x16x32_bf16(p0, onesf, Lacc[m], 0, 0, 0);
            Lacc[m] = __builtin_amdgcn_mfma_f32_16x16x32_bf16(p1, onesf, Lacc[m], 0, 0, 0);
        }
    }
#undef PREFETCH

    // epilogue: denominator lives at col0==0 lanes of each quad; broadcast + scale + store
    #pragma unroll
    for (int m = 0; m < 2; m++) {
        float rl[4];
        #pragma unroll
        for (int reg = 0; reg < 4; reg++) {
            const float lsum = __shfl(Lacc[m][reg], lane & 48, 64);   // lane (quad*16 + 0)
            rl[reg] = 1.f / lsum;
        }
        #pragma unroll
        for (int nt = 0; nt < 4; nt++)
            #pragma unroll
            for (int reg = 0; reg < 4; reg++) {
                const int q = qbase[m] + r0 + reg;
                const int d = nt * 16 + col0;
                ctx[((size_t)b * S_ + q) * H_ + h * HD_ + d] = f2bf_rn(Oacc[m][nt][reg] * rl[reg]);
            }
    }
}

// ---------------------------------------------------------------- launch
extern "C" void kernel_launch(void* const* d_in, const int* in_sizes, int n_in,
                              void* d_out, int out_size, void* d_ws, size_t ws_size,
                              hipStream_t stream) {
    const float* x     = (const float*)d_in[0];
    const int*   mask  = (const int*)d_in[1];
    const float* normw = (const float*)d_in[2];
    const float* normb = (const float*)d_in[3];
    const float* qkvw  = (const float*)d_in[4];
    const float* qkvb  = (const float*)d_in[5];
    const float* ow    = (const float*)d_in[6];
    const float* ob    = (const float*)d_in[7];
    float* out = (float*)d_out;

    char* ws = (char*)d_ws;
    unsigned short* xn_bf   = (unsigned short*)(ws);                      //  8 MB
    unsigned short* qkvwT   = (unsigned short*)(ws + (8ull  << 20));      //  6 MB
    unsigned short* owT     = (unsigned short*)(ws + (14ull << 20));      //  2 MB
    unsigned short* qkv_bf  = (unsigned short*)(ws + (16ull << 20));      // 24 MB
    unsigned short* Qb      = (unsigned short*)(ws + (40ull << 20));      //  8 MB [bh][s][d]
    unsigned short* Kb      = (unsigned short*)(ws + (48ull << 20));      //  8 MB [bh][s][d]
    unsigned short* Vtb     = (unsigned short*)(ws + (56ull << 20));      //  8 MB [bh][d][s]
    unsigned short* ctx_bf  = (unsigned short*)(ws + (64ull << 20));      //  8 MB

    cvt_transpose_k<<<dim3(H3_ / 64, H_ / 64), 256, 0, stream>>>(qkvw, qkvwT, H_, H3_);
    cvt_transpose_k<<<dim3(H_  / 64, H_ / 64), 256, 0, stream>>>(ow,   owT,   H_, H_);
    layernorm_k<<<T_, 256, 0, stream>>>(x, normw, normb, xn_bf);
    gemm_bf16<false><<<dim3(H3_ / BN, T_ / BM), 256, 0, stream>>>(xn_bf, qkvwT, qkvb,
                                                                  nullptr, qkv_bf, T_, H3_, H_);
    rotary_qk_k<<<T_, 256, 0, stream>>>(qkv_bf, Qb, Kb);
    v_transpose_k<<<dim3(S_ / 64, B_), 256, 0, stream>>>(qkv_bf, Vtb);
    attn_k<<<512, 256, 0, stream>>>(Qb, Kb, Vtb, mask, ctx_bf);
    gemm_bf16<true><<<dim3(H_ / BN, T_ / BM), 256, 0, stream>>>(ctx_bf, owT, ob,
                                                                out, nullptr, T_, H_, H_);
}

// Round 6
// 224.951 us; speedup vs baseline: 1.6624x; 1.1213x over previous
//
#include <hip/hip_runtime.h>
#include <hip/hip_bf16.h>

#define B_  2
#define S_  2048
#define H_  1024
#define NH_ 16
#define HD_ 64
#define T_  (B_*S_)     // 4096 tokens
#define H3_ (3*H_)      // 3072

typedef float  floatx4 __attribute__((ext_vector_type(4)));
typedef __bf16 bf16x8  __attribute__((ext_vector_type(8)));

__device__ inline unsigned short f2bf_rn(float f) {
    union { float f; unsigned int u; } v; v.f = f;
    unsigned int u = v.u;
    u += 0x7fffu + ((u >> 16) & 1u);
    return (unsigned short)(u >> 16);
}
__device__ inline unsigned short f2bf_tr(float f) {   // truncate (1 op) — self-consistent w/ MFMA-summed l
    union { float f; unsigned int u; } v; v.f = f;
    return (unsigned short)(v.u >> 16);
}
__device__ inline floatx4 fzero4() { floatx4 v; v[0]=0.f; v[1]=0.f; v[2]=0.f; v[3]=0.f; return v; }

// async global->LDS, 16B per lane; LDS dest = wave-uniform base + lane*16
__device__ inline void gload_lds16(const unsigned short* g, unsigned short* l) {
    __builtin_amdgcn_global_load_lds((const __attribute__((address_space(1))) unsigned int*)g,
                                     (__attribute__((address_space(3))) unsigned int*)l,
                                     16, 0, 0);
}

// ---------------------------------------------------------------- fused cast + transpose: W[K][N] f32 -> Wt[N][K] bf16
#define TLD 72
__global__ __launch_bounds__(256) void cvt_transpose_k(const float* __restrict__ W,
                                                       unsigned short* __restrict__ Wt,
                                                       int K, int N) {
    __shared__ unsigned short Ts[64 * TLD];
    const int nb = blockIdx.x * 64;
    const int kb = blockIdx.y * 64;
    const int tid = threadIdx.x;
    #pragma unroll
    for (int p = 0; p < 4; p++) {
        const int krow = kb + p * 16 + (tid >> 4);
        const int ncol = (tid & 15) * 4;
        const float4 w = *reinterpret_cast<const float4*>(&W[(size_t)krow * N + nb + ncol]);
        Ts[(ncol + 0) * TLD + p * 16 + (tid >> 4)] = f2bf_rn(w.x);
        Ts[(ncol + 1) * TLD + p * 16 + (tid >> 4)] = f2bf_rn(w.y);
        Ts[(ncol + 2) * TLD + p * 16 + (tid >> 4)] = f2bf_rn(w.z);
        Ts[(ncol + 3) * TLD + p * 16 + (tid >> 4)] = f2bf_rn(w.w);
    }
    __syncthreads();
    #pragma unroll
    for (int p = 0; p < 2; p++) {
        const int n = (tid >> 3) + p * 32;
        const int k8 = (tid & 7) * 8;
        const uint4 v = *reinterpret_cast<const uint4*>(&Ts[n * TLD + k8]);
        *reinterpret_cast<uint4*>(&Wt[(size_t)(nb + n) * K + kb + k8]) = v;
    }
}

// ---------------------------------------------------------------- LayerNorm (fp32 stats, bf16 out)
__global__ __launch_bounds__(256) void layernorm_k(const float* __restrict__ x,
                                                   const float* __restrict__ w,
                                                   const float* __restrict__ b,
                                                   unsigned short* __restrict__ xn) {
    const int t   = blockIdx.x;
    const int tid = threadIdx.x;
    const float4 v = reinterpret_cast<const float4*>(x + (size_t)t * H_)[tid];
    float s  = v.x + v.y + v.z + v.w;
    float s2 = v.x*v.x + v.y*v.y + v.z*v.z + v.w*v.w;
    for (int off = 32; off > 0; off >>= 1) {
        s  += __shfl_down(s,  off, 64);
        s2 += __shfl_down(s2, off, 64);
    }
    __shared__ float red[8];
    const int wave = tid >> 6, lane = tid & 63;
    if (lane == 0) { red[wave] = s; red[4 + wave] = s2; }
    __syncthreads();
    if (tid == 0) {
        red[0] = red[0] + red[1] + red[2] + red[3];
        red[4] = red[4] + red[5] + red[6] + red[7];
    }
    __syncthreads();
    const float mean = red[0] * (1.f / H_);
    const float var  = red[4] * (1.f / H_) - mean * mean;
    const float rstd = rsqrtf(var + 1e-5f);
    const float4 wv = reinterpret_cast<const float4*>(w)[tid];
    const float4 bv = reinterpret_cast<const float4*>(b)[tid];
    ushort4 o = make_ushort4(f2bf_rn((v.x - mean) * rstd * wv.x + bv.x),
                             f2bf_rn((v.y - mean) * rstd * wv.y + bv.y),
                             f2bf_rn((v.z - mean) * rstd * wv.z + bv.z),
                             f2bf_rn((v.w - mean) * rstd * wv.w + bv.w));
    reinterpret_cast<ushort4*>(xn + (size_t)t * H_)[tid] = o;
}

// ---------------------------------------------------------------- bf16 MFMA GEMM  C = A(MxK) @ Bt(NxK)^T + bias
// m97 recipe: 128x128 tile, BK=32, single-buffer unpadded LDS, global_load_lds width16, 2-barrier K-loop.
#define BM 128
#define BN 128
#define BK 32

template <bool OUT_F32>
__global__ __launch_bounds__(256) void gemm_bf16(const unsigned short* __restrict__ A,
                                                 const unsigned short* __restrict__ Bt,
                                                 const float* __restrict__ bias,
                                                 float* __restrict__ Cf,
                                                 unsigned short* __restrict__ Cb,
                                                 int M, int N, int K) {
    __shared__ unsigned short As[BM * BK];
    __shared__ unsigned short Bs[BN * BK];

    const int tid  = threadIdx.x;
    const int lane = tid & 63;
    const int wave = tid >> 6;
    const int wr = wave >> 1, wc = wave & 1;
    const int mBase = blockIdx.y * BM;
    const int nBase = blockIdx.x * BN;

    floatx4 acc[4][4];
    #pragma unroll
    for (int i = 0; i < 4; i++)
        #pragma unroll
        for (int j = 0; j < 4; j++) acc[i][j] = fzero4();

    const int srow = lane >> 2;
    const int scol = (lane & 3) * 8;
    const int mrow = lane & 15;
    const int koff = (lane >> 4) * 8;

    for (int kb = 0; kb < K; kb += BK) {
        __syncthreads();
        #pragma unroll
        for (int p = 0; p < 2; p++) {
            const int r = wave * 16 + p * 64;
            gload_lds16(&A [(size_t)(mBase + r + srow) * K + kb + scol], &As[r * BK]);
            gload_lds16(&Bt[(size_t)(nBase + r + srow) * K + kb + scol], &Bs[r * BK]);
        }
        __syncthreads();

        bf16x8 afrag[4], bfrag[4];
        #pragma unroll
        for (int mt = 0; mt < 4; mt++)
            afrag[mt] = *reinterpret_cast<const bf16x8*>(&As[(wr * 64 + mt * 16 + mrow) * BK + koff]);
        #pragma unroll
        for (int nt = 0; nt < 4; nt++)
            bfrag[nt] = *reinterpret_cast<const bf16x8*>(&Bs[(wc * 64 + nt * 16 + mrow) * BK + koff]);
        #pragma unroll
        for (int mt = 0; mt < 4; mt++)
            #pragma unroll
            for (int nt = 0; nt < 4; nt++)
                acc[mt][nt] = __builtin_amdgcn_mfma_f32_16x16x32_bf16(afrag[mt], bfrag[nt], acc[mt][nt], 0, 0, 0);
    }

    const int col0 = lane & 15;
    const int r0   = (lane >> 4) * 4;
    #pragma unroll
    for (int mt = 0; mt < 4; mt++) {
        #pragma unroll
        for (int nt = 0; nt < 4; nt++) {
            const int gcol = nBase + wc * 64 + nt * 16 + col0;
            const float bs = bias[gcol];
            #pragma unroll
            for (int reg = 0; reg < 4; reg++) {
                const int grow = mBase + wr * 64 + mt * 16 + r0 + reg;
                const float v = acc[mt][nt][reg] + bs;
                if constexpr (OUT_F32) Cf[(size_t)grow * N + gcol] = v;
                else                   Cb[(size_t)grow * N + gcol] = f2bf_rn(v);
            }
        }
    }
}

// ---------------------------------------------------------------- rotary for q,k -> Q/K [b,h,s,d] bf16
__global__ __launch_bounds__(256) void rotary_qk_k(const unsigned short* __restrict__ qkv,
                                                   unsigned short* __restrict__ Q,
                                                   unsigned short* __restrict__ K) {
    const int t   = blockIdx.x;
    const int b   = t / S_;
    const int s   = t % S_;
    const int tid = threadIdx.x;
    const unsigned short* row = qkv + (size_t)t * H3_;
    #pragma unroll
    for (int i = 0; i < 4; i++) {
        const int idx = tid + i * 256;    // h*64 + d
        const int h = idx >> 6, d = idx & 63;
        const float inv_freq = __expf((float)(d & 31) * (-0.2878231366f)); // -ln(10000)/32
        const float fr = (float)s * inv_freq;
        float sn, cs;
        __sincosf(fr, &sn, &cs);
        const size_t dst = ((size_t)(b * NH_ + h) * S_ + s) * HD_ + d;
        {
            union { unsigned int u; float f; } a, p;
            a.u = ((unsigned int)row[idx]) << 16;
            p.u = ((unsigned int)row[idx ^ 32]) << 16;
            const float rot = (d < 32) ? -p.f : p.f;
            Q[dst] = f2bf_rn(a.f * cs + rot * sn);
        }
        {
            union { unsigned int u; float f; } a, p;
            a.u = ((unsigned int)row[H_ + idx]) << 16;
            p.u = ((unsigned int)row[H_ + (idx ^ 32)]) << 16;
            const float rot = (d < 32) ? -p.f : p.f;
            K[dst] = f2bf_rn(a.f * cs + rot * sn);
        }
    }
}

// ---------------------------------------------------------------- V transpose: qkv v-part -> Vt[bh][d][s]
__global__ __launch_bounds__(256) void v_transpose_k(const unsigned short* __restrict__ qkv,
                                                     unsigned short* __restrict__ Vt) {
    __shared__ unsigned short Vs[64 * TLD];
    const int s0 = blockIdx.x * 64;
    const int b  = blockIdx.y;
    const int tid = threadIdx.x;
    for (int h = 0; h < NH_; h++) {
        __syncthreads();
        #pragma unroll
        for (int p = 0; p < 2; p++) {
            const int tl = tid >> 2;
            const int c  = (tid & 3) * 8 + p * 32;
            const uint4 v = *reinterpret_cast<const uint4*>(
                &qkv[(size_t)(b * S_ + s0 + tl) * H3_ + 2 * H_ + h * 64 + c]);
            *reinterpret_cast<uint4*>(&Vs[tl * TLD + c]) = v;
        }
        __syncthreads();
        #pragma unroll
        for (int p = 0; p < 2; p++) {
            const int d  = (tid >> 3) + p * 32;
            const int s8 = (tid & 7) * 8;
            unsigned short tmp[8];
            #pragma unroll
            for (int jj = 0; jj < 8; jj++) tmp[jj] = Vs[(s8 + jj) * TLD + d];
            *reinterpret_cast<uint4*>(&Vt[((size_t)(b * NH_ + h) * HD_ + d) * S_ + s0 + s8]) =
                *reinterpret_cast<uint4*>(tmp);
        }
    }
}

// ---------------------------------------------------------------- flash attention
// fixed-max (m=0) log2-softmax; l via MFMA ones-column; one 64-row q-band per block;
// single-buffer LDS (27.6 KB -> 4 blocks/CU); longest bands dispatched first; bh pinned to XCD.
#define ALD 72
#define SCL2 0.1803368801f      /* 0.125 * log2(e) */
#define MNEG -14427.0f          /* -10000 * log2(e), causal fill */

__global__ __launch_bounds__(256, 4) void attn_k(const unsigned short* __restrict__ Q,
                                                 const unsigned short* __restrict__ Kg,
                                                 const unsigned short* __restrict__ Vt,
                                                 const int* __restrict__ mask,
                                                 unsigned short* __restrict__ ctx) {
    const int id = blockIdx.x;              // 0..1023
    const int bh = id & 31;                 // id%8 fixed per bh -> XCD locality
    const int v  = 31 - (id >> 5);          // q-tile index; most work first
    const int b  = bh >> 4;
    const int h  = bh & 15;
    const int tid  = threadIdx.x;
    const int lane = tid & 63;
    const int wave = tid >> 6;

    __shared__ unsigned short Ks [64 * ALD];     // 9.2 KB
    __shared__ unsigned short Vts[64 * ALD];     // 9.2 KB
    __shared__ unsigned short Ps[4][16 * ALD];   // 9.2 KB

    const size_t base = (size_t)bh * S_ * HD_;
    const int qbase = v * 64 + wave * 16;
    const int mrow = lane & 15;
    const int koff = (lane >> 4) * 8;
    const int r0   = (lane >> 4) * 4;
    const int col0 = lane & 15;

    bf16x8 qf0 = *reinterpret_cast<const bf16x8*>(&Q[base + (size_t)(qbase + mrow) * HD_ + koff]);
    bf16x8 qf1 = *reinterpret_cast<const bf16x8*>(&Q[base + (size_t)(qbase + mrow) * HD_ + 32 + koff]);

    // ones B-fragment: B[k][n] = (n==0)
    bf16x8 onesf;
    {
        const __bf16 ov = (__bf16)((mrow == 0) ? 1.f : 0.f);
        #pragma unroll
        for (int q = 0; q < 8; q++) onesf[q] = ov;
    }

    floatx4 Oacc[4];
    floatx4 Lacc = fzero4();
    #pragma unroll
    for (int nt = 0; nt < 4; nt++) Oacc[nt] = fzero4();

    const int srow = tid >> 3;          // 0..31
    const int scol = (tid & 7) * 8;

    uint4 kreg0, kreg1, vreg0, vreg1;
    float mb0, mb1, mb2, mb3;
#define PREFETCH(KT) do {                                                                      \
        const int kb_ = (KT) * 64;                                                             \
        kreg0 = *reinterpret_cast<const uint4*>(&Kg[base + (size_t)(kb_ + srow)      * HD_ + scol]); \
        kreg1 = *reinterpret_cast<const uint4*>(&Kg[base + (size_t)(kb_ + srow + 32) * HD_ + scol]); \
        vreg0 = *reinterpret_cast<const uint4*>(&Vt[base + (size_t)srow        * S_ + kb_ + scol]);  \
        vreg1 = *reinterpret_cast<const uint4*>(&Vt[base + (size_t)(srow + 32) * S_ + kb_ + scol]);  \
        mb0 = (1.f - (float)mask[b * S_ + kb_ +  0 + col0]) * MNEG;                            \
        mb1 = (1.f - (float)mask[b * S_ + kb_ + 16 + col0]) * MNEG;                            \
        mb2 = (1.f - (float)mask[b * S_ + kb_ + 32 + col0]) * MNEG;                            \
        mb3 = (1.f - (float)mask[b * S_ + kb_ + 48 + col0]) * MNEG;                            \
    } while (0)

    PREFETCH(0);

    unsigned short* pw = Ps[wave];

    for (int kt = 0; kt <= v; kt++) {
        const int kb = kt * 64;
        if (kt) __syncthreads();                       // WAR: prior iter's LDS reads done
        *reinterpret_cast<uint4*>(&Ks [ srow       * ALD + scol]) = kreg0;
        *reinterpret_cast<uint4*>(&Ks [(srow + 32) * ALD + scol]) = kreg1;
        *reinterpret_cast<uint4*>(&Vts[ srow       * ALD + scol]) = vreg0;
        *reinterpret_cast<uint4*>(&Vts[(srow + 32) * ALD + scol]) = vreg1;
        __syncthreads();
        const float mc0 = mb0, mc1 = mb1, mc2 = mb2, mc3 = mb3;
        if (kt < v) PREFETCH(kt + 1);

        // ---- S = Q K^T, scale+bias in log2 domain
        floatx4 sc[4];
        #pragma unroll
        for (int nt = 0; nt < 4; nt++) {
            const bf16x8 k0 = *reinterpret_cast<const bf16x8*>(&Ks[(nt * 16 + mrow) * ALD + koff]);
            const bf16x8 k1 = *reinterpret_cast<const bf16x8*>(&Ks[(nt * 16 + mrow) * ALD + 32 + koff]);
            floatx4 c = fzero4();
            c = __builtin_amdgcn_mfma_f32_16x16x32_bf16(qf0, k0, c, 0, 0, 0);
            c = __builtin_amdgcn_mfma_f32_16x16x32_bf16(qf1, k1, c, 0, 0, 0);
            sc[nt] = c;
        }
        #pragma unroll
        for (int nt = 0; nt < 4; nt++) {
            const float mbv = (nt == 0) ? mc0 : (nt == 1) ? mc1 : (nt == 2) ? mc2 : mc3;
            #pragma unroll
            for (int reg = 0; reg < 4; reg++)
                sc[nt][reg] = sc[nt][reg] * SCL2 + mbv;
        }
        // ---- causal (diagonal tile only; wave-uniform branch)
        if (kt == v) {
            #pragma unroll
            for (int nt = 0; nt < 4; nt++) {
                const int key = kb + nt * 16 + col0;
                #pragma unroll
                for (int reg = 0; reg < 4; reg++)
                    if (key > qbase + r0 + reg) sc[nt][reg] = MNEG;
            }
        }
        // ---- P = exp2(s), truncate-store to LDS (A-layout rows); no max, no rescale
        #pragma unroll
        for (int nt = 0; nt < 4; nt++)
            #pragma unroll
            for (int reg = 0; reg < 4; reg++)
                pw[(r0 + reg) * ALD + nt * 16 + col0] = f2bf_tr(exp2f(sc[nt][reg]));
        // ---- PV (+ ones-column for denominator)
        const bf16x8 p0 = *reinterpret_cast<const bf16x8*>(&pw[mrow * ALD + koff]);
        const bf16x8 p1 = *reinterpret_cast<const bf16x8*>(&pw[mrow * ALD + 32 + koff]);
        #pragma unroll
        for (int nt = 0; nt < 4; nt++) {
            const bf16x8 v0 = *reinterpret_cast<const bf16x8*>(&Vts[(nt * 16 + mrow) * ALD + koff]);
            const bf16x8 v1 = *reinterpret_cast<const bf16x8*>(&Vts[(nt * 16 + mrow) * ALD + 32 + koff]);
            Oacc[nt] = __builtin_amdgcn_mfma_f32_16x16x32_bf16(p0, v0, Oacc[nt], 0, 0, 0);
            Oacc[nt] = __builtin_amdgcn_mfma_f32_16x16x32_bf16(p1, v1, Oacc[nt], 0, 0, 0);
        }
        Lacc = __builtin_amdgcn_mfma_f32_16x16x32_bf16(p0, onesf, Lacc, 0, 0, 0);
        Lacc = __builtin_amdgcn_mfma_f32_16x16x32_bf16(p1, onesf, Lacc, 0, 0, 0);
    }
#undef PREFETCH

    // epilogue: denominator lives in column 0 lanes (quad*16); broadcast + scale + store
    float rl[4];
    #pragma unroll
    for (int reg = 0; reg < 4; reg++) {
        const float lsum = __shfl(Lacc[reg], lane & 48, 64);
        rl[reg] = 1.f / lsum;
    }
    #pragma unroll
    for (int nt = 0; nt < 4; nt++)
        #pragma unroll
        for (int reg = 0; reg < 4; reg++) {
            const int q = qbase + r0 + reg;
            const int d = nt * 16 + col0;
            ctx[((size_t)b * S_ + q) * H_ + h * HD_ + d] = f2bf_rn(Oacc[nt][reg] * rl[reg]);
        }
}

// ---------------------------------------------------------------- launch
extern "C" void kernel_launch(void* const* d_in, const int* in_sizes, int n_in,
                              void* d_out, int out_size, void* d_ws, size_t ws_size,
                              hipStream_t stream) {
    const float* x     = (const float*)d_in[0];
    const int*   mask  = (const int*)d_in[1];
    const float* normw = (const float*)d_in[2];
    const float* normb = (const float*)d_in[3];
    const float* qkvw  = (const float*)d_in[4];
    const float* qkvb  = (const float*)d_in[5];
    const float* ow    = (const float*)d_in[6];
    const float* ob    = (const float*)d_in[7];
    float* out = (float*)d_out;

    char* ws = (char*)d_ws;
    unsigned short* xn_bf   = (unsigned short*)(ws);                      //  8 MB
    unsigned short* qkvwT   = (unsigned short*)(ws + (8ull  << 20));      //  6 MB
    unsigned short* owT     = (unsigned short*)(ws + (14ull << 20));      //  2 MB
    unsigned short* qkv_bf  = (unsigned short*)(ws + (16ull << 20));      // 24 MB
    unsigned short* Qb      = (unsigned short*)(ws + (40ull << 20));      //  8 MB [bh][s][d]
    unsigned short* Kb      = (unsigned short*)(ws + (48ull << 20));      //  8 MB [bh][s][d]
    unsigned short* Vtb     = (unsigned short*)(ws + (56ull << 20));      //  8 MB [bh][d][s]
    unsigned short* ctx_bf  = (unsigned short*)(ws + (64ull << 20));      //  8 MB

    cvt_transpose_k<<<dim3(H3_ / 64, H_ / 64), 256, 0, stream>>>(qkvw, qkvwT, H_, H3_);
    cvt_transpose_k<<<dim3(H_  / 64, H_ / 64), 256, 0, stream>>>(ow,   owT,   H_, H_);
    layernorm_k<<<T_, 256, 0, stream>>>(x, normw, normb, xn_bf);
    gemm_bf16<false><<<dim3(H3_ / BN, T_ / BM), 256, 0, stream>>>(xn_bf, qkvwT, qkvb,
                                                                  nullptr, qkv_bf, T_, H3_, H_);
    rotary_qk_k<<<T_, 256, 0, stream>>>(qkv_bf, Qb, Kb);
    v_transpose_k<<<dim3(S_ / 64, B_), 256, 0, stream>>>(qkv_bf, Vtb);
    attn_k<<<1024, 256, 0, stream>>>(Qb, Kb, Vtb, mask, ctx_bf);
    gemm_bf16<true><<<dim3(H_ / BN, T_ / BM), 256, 0, stream>>>(ctx_bf, owT, ob,
                                                                out, nullptr, T_, H_, H_);
}

// Round 7
// 213.223 us; speedup vs baseline: 1.7538x; 1.0550x over previous
//
#include <hip/hip_runtime.h>
#include <hip/hip_bf16.h>

#define B_  2
#define S_  2048
#define H_  1024
#define NH_ 16
#define HD_ 64
#define T_  (B_*S_)     // 4096 tokens
#define H3_ (3*H_)      // 3072

typedef float  floatx4 __attribute__((ext_vector_type(4)));
typedef __bf16 bf16x8  __attribute__((ext_vector_type(8)));

__device__ inline unsigned short f2bf_rn(float f) {
    union { float f; unsigned int u; } v; v.f = f;
    unsigned int u = v.u;
    u += 0x7fffu + ((u >> 16) & 1u);
    return (unsigned short)(u >> 16);
}
__device__ inline unsigned short f2bf_tr(float f) {   // truncate — self-consistent w/ MFMA-summed l
    union { float f; unsigned int u; } v; v.f = f;
    return (unsigned short)(v.u >> 16);
}
__device__ inline floatx4 fzero4() { floatx4 v; v[0]=0.f; v[1]=0.f; v[2]=0.f; v[3]=0.f; return v; }

// async global->LDS, 16B per lane; LDS dest = wave-uniform base + lane*16
__device__ inline void gload_lds16(const unsigned short* g, unsigned short* l) {
    __builtin_amdgcn_global_load_lds((const __attribute__((address_space(1))) unsigned int*)g,
                                     (__attribute__((address_space(3))) unsigned int*)l,
                                     16, 0, 0);
}

// ---------------------------------------------------------------- fused cast + transpose: W[K][N] f32 -> Wt[N][K] bf16
#define TLD 72
__global__ __launch_bounds__(256) void cvt_transpose_k(const float* __restrict__ W,
                                                       unsigned short* __restrict__ Wt,
                                                       int K, int N) {
    __shared__ unsigned short Ts[64 * TLD];
    const int nb = blockIdx.x * 64;
    const int kb = blockIdx.y * 64;
    const int tid = threadIdx.x;
    #pragma unroll
    for (int p = 0; p < 4; p++) {
        const int krow = kb + p * 16 + (tid >> 4);
        const int ncol = (tid & 15) * 4;
        const float4 w = *reinterpret_cast<const float4*>(&W[(size_t)krow * N + nb + ncol]);
        Ts[(ncol + 0) * TLD + p * 16 + (tid >> 4)] = f2bf_rn(w.x);
        Ts[(ncol + 1) * TLD + p * 16 + (tid >> 4)] = f2bf_rn(w.y);
        Ts[(ncol + 2) * TLD + p * 16 + (tid >> 4)] = f2bf_rn(w.z);
        Ts[(ncol + 3) * TLD + p * 16 + (tid >> 4)] = f2bf_rn(w.w);
    }
    __syncthreads();
    #pragma unroll
    for (int p = 0; p < 2; p++) {
        const int n = (tid >> 3) + p * 32;
        const int k8 = (tid & 7) * 8;
        const uint4 v = *reinterpret_cast<const uint4*>(&Ts[n * TLD + k8]);
        *reinterpret_cast<uint4*>(&Wt[(size_t)(nb + n) * K + kb + k8]) = v;
    }
}

// ---------------------------------------------------------------- LayerNorm (fp32 stats, bf16 out)
__global__ __launch_bounds__(256) void layernorm_k(const float* __restrict__ x,
                                                   const float* __restrict__ w,
                                                   const float* __restrict__ b,
                                                   unsigned short* __restrict__ xn) {
    const int t   = blockIdx.x;
    const int tid = threadIdx.x;
    const float4 v = reinterpret_cast<const float4*>(x + (size_t)t * H_)[tid];
    float s  = v.x + v.y + v.z + v.w;
    float s2 = v.x*v.x + v.y*v.y + v.z*v.z + v.w*v.w;
    for (int off = 32; off > 0; off >>= 1) {
        s  += __shfl_down(s,  off, 64);
        s2 += __shfl_down(s2, off, 64);
    }
    __shared__ float red[8];
    const int wave = tid >> 6, lane = tid & 63;
    if (lane == 0) { red[wave] = s; red[4 + wave] = s2; }
    __syncthreads();
    if (tid == 0) {
        red[0] = red[0] + red[1] + red[2] + red[3];
        red[4] = red[4] + red[5] + red[6] + red[7];
    }
    __syncthreads();
    const float mean = red[0] * (1.f / H_);
    const float var  = red[4] * (1.f / H_) - mean * mean;
    const float rstd = rsqrtf(var + 1e-5f);
    const float4 wv = reinterpret_cast<const float4*>(w)[tid];
    const float4 bv = reinterpret_cast<const float4*>(b)[tid];
    ushort4 o = make_ushort4(f2bf_rn((v.x - mean) * rstd * wv.x + bv.x),
                             f2bf_rn((v.y - mean) * rstd * wv.y + bv.y),
                             f2bf_rn((v.z - mean) * rstd * wv.z + bv.z),
                             f2bf_rn((v.w - mean) * rstd * wv.w + bv.w));
    reinterpret_cast<ushort4*>(xn + (size_t)t * H_)[tid] = o;
}

// ---------------------------------------------------------------- GEMM core macro pieces (m97 recipe)
#define BM 128
#define BN 128
#define BK 32

// ---------------------------------------------------------------- QKV GEMM with fused bias+rotary+V-transpose epilogue
// C = xn(T x H) @ qkvwT(3H x H)^T; wave tile = 64 cols = exactly one head -> wave-uniform section.
// Rotary partner d^32 lives in the same lane at nt^2. Writes Q/K [bh][s][d], Vt [bh][d][s] directly.
__global__ __launch_bounds__(256) void gemm_qkv_k(const unsigned short* __restrict__ A,
                                                  const unsigned short* __restrict__ Bt,
                                                  const float* __restrict__ bias,
                                                  unsigned short* __restrict__ Qo,
                                                  unsigned short* __restrict__ Ko,
                                                  unsigned short* __restrict__ Vto) {
    __shared__ unsigned short As[BM * BK];
    __shared__ unsigned short Bs[BN * BK];

    const int tid  = threadIdx.x;
    const int lane = tid & 63;
    const int wave = tid >> 6;
    const int wr = wave >> 1, wc = wave & 1;
    const int mBase = blockIdx.y * BM;
    const int nBase = blockIdx.x * BN;
    const int K = H_, M = T_;
    (void)M;

    floatx4 acc[4][4];
    #pragma unroll
    for (int i = 0; i < 4; i++)
        #pragma unroll
        for (int j = 0; j < 4; j++) acc[i][j] = fzero4();

    const int srow = lane >> 2;
    const int scol = (lane & 3) * 8;
    const int mrow = lane & 15;
    const int koff = (lane >> 4) * 8;

    for (int kb = 0; kb < K; kb += BK) {
        __syncthreads();
        #pragma unroll
        for (int p = 0; p < 2; p++) {
            const int r = wave * 16 + p * 64;
            gload_lds16(&A [(size_t)(mBase + r + srow) * K + kb + scol], &As[r * BK]);
            gload_lds16(&Bt[(size_t)(nBase + r + srow) * K + kb + scol], &Bs[r * BK]);
        }
        __syncthreads();

        bf16x8 afrag[4], bfrag[4];
        #pragma unroll
        for (int mt = 0; mt < 4; mt++)
            afrag[mt] = *reinterpret_cast<const bf16x8*>(&As[(wr * 64 + mt * 16 + mrow) * BK + koff]);
        #pragma unroll
        for (int nt = 0; nt < 4; nt++)
            bfrag[nt] = *reinterpret_cast<const bf16x8*>(&Bs[(wc * 64 + nt * 16 + mrow) * BK + koff]);
        #pragma unroll
        for (int mt = 0; mt < 4; mt++)
            #pragma unroll
            for (int nt = 0; nt < 4; nt++)
                acc[mt][nt] = __builtin_amdgcn_mfma_f32_16x16x32_bf16(afrag[mt], bfrag[nt], acc[mt][nt], 0, 0, 0);
    }

    const int col0 = lane & 15;
    const int r0   = (lane >> 4) * 4;
    const int hg   = (nBase + wc * 64) >> 6;   // global head index 0..47 (wave-uniform)
    const int sec  = hg >> 4;                  // 0=q 1=k 2=v
    const int h    = hg & 15;

    float bs[4];
    #pragma unroll
    for (int nt = 0; nt < 4; nt++) bs[nt] = bias[nBase + wc * 64 + nt * 16 + col0];

    if (sec < 2) {
        unsigned short* dst = (sec == 0) ? Qo : Ko;
        const float if0 = __expf((float)col0        * (-0.2878231366f));   // j = col0
        const float if1 = __expf((float)(16 + col0) * (-0.2878231366f));   // j = 16+col0
        #pragma unroll
        for (int mt = 0; mt < 4; mt++) {
            #pragma unroll
            for (int reg = 0; reg < 4; reg++) {
                const int t  = mBase + wr * 64 + mt * 16 + r0 + reg;
                const int bb = t >> 11;
                const int s  = t & (S_ - 1);
                float sn0, cs0, sn1, cs1;
                __sincosf((float)s * if0, &sn0, &cs0);
                __sincosf((float)s * if1, &sn1, &cs1);
                const float v0 = acc[mt][0][reg] + bs[0];   // d = col0
                const float v1 = acc[mt][1][reg] + bs[1];   // d = 16+col0
                const float v2 = acc[mt][2][reg] + bs[2];   // d = 32+col0
                const float v3 = acc[mt][3][reg] + bs[3];   // d = 48+col0
                const float o0 = v0 * cs0 - v2 * sn0;
                const float o1 = v1 * cs1 - v3 * sn1;
                const float o2 = v2 * cs0 + v0 * sn0;
                const float o3 = v3 * cs1 + v1 * sn1;
                const size_t rb = ((size_t)(bb * NH_ + h) * S_ + s) * HD_;
                dst[rb +      col0] = f2bf_rn(o0);
                dst[rb + 16 + col0] = f2bf_rn(o1);
                dst[rb + 32 + col0] = f2bf_rn(o2);
                dst[rb + 48 + col0] = f2bf_rn(o3);
            }
        }
    } else {
        #pragma unroll
        for (int mt = 0; mt < 4; mt++) {
            const int t0 = mBase + wr * 64 + mt * 16 + r0;   // 4 consecutive tokens, 4-aligned
            const int bb = t0 >> 11;
            const int s0 = t0 & (S_ - 1);
            #pragma unroll
            for (int nt = 0; nt < 4; nt++) {
                const int d = nt * 16 + col0;
                ushort4 o;
                o.x = f2bf_rn(acc[mt][nt][0] + bs[nt]);
                o.y = f2bf_rn(acc[mt][nt][1] + bs[nt]);
                o.z = f2bf_rn(acc[mt][nt][2] + bs[nt]);
                o.w = f2bf_rn(acc[mt][nt][3] + bs[nt]);
                *reinterpret_cast<ushort4*>(&Vto[((size_t)(bb * NH_ + h) * HD_ + d) * S_ + s0]) = o;
            }
        }
    }
}

// ---------------------------------------------------------------- generic bf16 MFMA GEMM (proj): C = A @ Bt^T + bias (f32 out)
__global__ __launch_bounds__(256) void gemm_proj_k(const unsigned short* __restrict__ A,
                                                   const unsigned short* __restrict__ Bt,
                                                   const float* __restrict__ bias,
                                                   float* __restrict__ Cf,
                                                   int M, int N, int K) {
    __shared__ unsigned short As[BM * BK];
    __shared__ unsigned short Bs[BN * BK];

    const int tid  = threadIdx.x;
    const int lane = tid & 63;
    const int wave = tid >> 6;
    const int wr = wave >> 1, wc = wave & 1;
    const int mBase = blockIdx.y * BM;
    const int nBase = blockIdx.x * BN;

    floatx4 acc[4][4];
    #pragma unroll
    for (int i = 0; i < 4; i++)
        #pragma unroll
        for (int j = 0; j < 4; j++) acc[i][j] = fzero4();

    const int srow = lane >> 2;
    const int scol = (lane & 3) * 8;
    const int mrow = lane & 15;
    const int koff = (lane >> 4) * 8;

    for (int kb = 0; kb < K; kb += BK) {
        __syncthreads();
        #pragma unroll
        for (int p = 0; p < 2; p++) {
            const int r = wave * 16 + p * 64;
            gload_lds16(&A [(size_t)(mBase + r + srow) * K + kb + scol], &As[r * BK]);
            gload_lds16(&Bt[(size_t)(nBase + r + srow) * K + kb + scol], &Bs[r * BK]);
        }
        __syncthreads();

        bf16x8 afrag[4], bfrag[4];
        #pragma unroll
        for (int mt = 0; mt < 4; mt++)
            afrag[mt] = *reinterpret_cast<const bf16x8*>(&As[(wr * 64 + mt * 16 + mrow) * BK + koff]);
        #pragma unroll
        for (int nt = 0; nt < 4; nt++)
            bfrag[nt] = *reinterpret_cast<const bf16x8*>(&Bs[(wc * 64 + nt * 16 + mrow) * BK + koff]);
        #pragma unroll
        for (int mt = 0; mt < 4; mt++)
            #pragma unroll
            for (int nt = 0; nt < 4; nt++)
                acc[mt][nt] = __builtin_amdgcn_mfma_f32_16x16x32_bf16(afrag[mt], bfrag[nt], acc[mt][nt], 0, 0, 0);
    }

    const int col0 = lane & 15;
    const int r0   = (lane >> 4) * 4;
    #pragma unroll
    for (int mt = 0; mt < 4; mt++) {
        #pragma unroll
        for (int nt = 0; nt < 4; nt++) {
            const int gcol = nBase + wc * 64 + nt * 16 + col0;
            const float bsv = bias[gcol];
            #pragma unroll
            for (int reg = 0; reg < 4; reg++) {
                const int grow = mBase + wr * 64 + mt * 16 + r0 + reg;
                Cf[(size_t)grow * N + gcol] = acc[mt][nt][reg] + bsv;
            }
        }
    }
}

// ---------------------------------------------------------------- flash attention (unchanged from R6)
#define ALD 72
#define SCL2 0.1803368801f      /* 0.125 * log2(e) */
#define MNEG -14427.0f          /* -10000 * log2(e), causal fill */

__global__ __launch_bounds__(256, 4) void attn_k(const unsigned short* __restrict__ Q,
                                                 const unsigned short* __restrict__ Kg,
                                                 const unsigned short* __restrict__ Vt,
                                                 const int* __restrict__ mask,
                                                 unsigned short* __restrict__ ctx) {
    const int id = blockIdx.x;              // 0..1023
    const int bh = id & 31;                 // id%8 fixed per bh -> XCD locality
    const int v  = 31 - (id >> 5);          // q-tile index; most work first
    const int b  = bh >> 4;
    const int h  = bh & 15;
    const int tid  = threadIdx.x;
    const int lane = tid & 63;
    const int wave = tid >> 6;

    __shared__ unsigned short Ks [64 * ALD];
    __shared__ unsigned short Vts[64 * ALD];
    __shared__ unsigned short Ps[4][16 * ALD];

    const size_t base = (size_t)bh * S_ * HD_;
    const int qbase = v * 64 + wave * 16;
    const int mrow = lane & 15;
    const int koff = (lane >> 4) * 8;
    const int r0   = (lane >> 4) * 4;
    const int col0 = lane & 15;

    bf16x8 qf0 = *reinterpret_cast<const bf16x8*>(&Q[base + (size_t)(qbase + mrow) * HD_ + koff]);
    bf16x8 qf1 = *reinterpret_cast<const bf16x8*>(&Q[base + (size_t)(qbase + mrow) * HD_ + 32 + koff]);

    bf16x8 onesf;
    {
        const __bf16 ov = (__bf16)((mrow == 0) ? 1.f : 0.f);
        #pragma unroll
        for (int q = 0; q < 8; q++) onesf[q] = ov;
    }

    floatx4 Oacc[4];
    floatx4 Lacc = fzero4();
    #pragma unroll
    for (int nt = 0; nt < 4; nt++) Oacc[nt] = fzero4();

    const int srow = tid >> 3;
    const int scol = (tid & 7) * 8;

    uint4 kreg0, kreg1, vreg0, vreg1;
    float mb0, mb1, mb2, mb3;
#define PREFETCH(KT) do {                                                                      \
        const int kb_ = (KT) * 64;                                                             \
        kreg0 = *reinterpret_cast<const uint4*>(&Kg[base + (size_t)(kb_ + srow)      * HD_ + scol]); \
        kreg1 = *reinterpret_cast<const uint4*>(&Kg[base + (size_t)(kb_ + srow + 32) * HD_ + scol]); \
        vreg0 = *reinterpret_cast<const uint4*>(&Vt[base + (size_t)srow        * S_ + kb_ + scol]);  \
        vreg1 = *reinterpret_cast<const uint4*>(&Vt[base + (size_t)(srow + 32) * S_ + kb_ + scol]);  \
        mb0 = (1.f - (float)mask[b * S_ + kb_ +  0 + col0]) * MNEG;                            \
        mb1 = (1.f - (float)mask[b * S_ + kb_ + 16 + col0]) * MNEG;                            \
        mb2 = (1.f - (float)mask[b * S_ + kb_ + 32 + col0]) * MNEG;                            \
        mb3 = (1.f - (float)mask[b * S_ + kb_ + 48 + col0]) * MNEG;                            \
    } while (0)

    PREFETCH(0);

    unsigned short* pw = Ps[wave];

    for (int kt = 0; kt <= v; kt++) {
        const int kb = kt * 64;
        if (kt) __syncthreads();
        *reinterpret_cast<uint4*>(&Ks [ srow       * ALD + scol]) = kreg0;
        *reinterpret_cast<uint4*>(&Ks [(srow + 32) * ALD + scol]) = kreg1;
        *reinterpret_cast<uint4*>(&Vts[ srow       * ALD + scol]) = vreg0;
        *reinterpret_cast<uint4*>(&Vts[(srow + 32) * ALD + scol]) = vreg1;
        __syncthreads();
        const float mc0 = mb0, mc1 = mb1, mc2 = mb2, mc3 = mb3;
        if (kt < v) PREFETCH(kt + 1);

        floatx4 sc[4];
        #pragma unroll
        for (int nt = 0; nt < 4; nt++) {
            const bf16x8 k0 = *reinterpret_cast<const bf16x8*>(&Ks[(nt * 16 + mrow) * ALD + koff]);
            const bf16x8 k1 = *reinterpret_cast<const bf16x8*>(&Ks[(nt * 16 + mrow) * ALD + 32 + koff]);
            floatx4 c = fzero4();
            c = __builtin_amdgcn_mfma_f32_16x16x32_bf16(qf0, k0, c, 0, 0, 0);
            c = __builtin_amdgcn_mfma_f32_16x16x32_bf16(qf1, k1, c, 0, 0, 0);
            sc[nt] = c;
        }
        #pragma unroll
        for (int nt = 0; nt < 4; nt++) {
            const float mbv = (nt == 0) ? mc0 : (nt == 1) ? mc1 : (nt == 2) ? mc2 : mc3;
            #pragma unroll
            for (int reg = 0; reg < 4; reg++)
                sc[nt][reg] = sc[nt][reg] * SCL2 + mbv;
        }
        if (kt == v) {
            #pragma unroll
            for (int nt = 0; nt < 4; nt++) {
                const int key = kb + nt * 16 + col0;
                #pragma unroll
                for (int reg = 0; reg < 4; reg++)
                    if (key > qbase + r0 + reg) sc[nt][reg] = MNEG;
            }
        }
        #pragma unroll
        for (int nt = 0; nt < 4; nt++)
            #pragma unroll
            for (int reg = 0; reg < 4; reg++)
                pw[(r0 + reg) * ALD + nt * 16 + col0] = f2bf_tr(exp2f(sc[nt][reg]));
        const bf16x8 p0 = *reinterpret_cast<const bf16x8*>(&pw[mrow * ALD + koff]);
        const bf16x8 p1 = *reinterpret_cast<const bf16x8*>(&pw[mrow * ALD + 32 + koff]);
        #pragma unroll
        for (int nt = 0; nt < 4; nt++) {
            const bf16x8 v0 = *reinterpret_cast<const bf16x8*>(&Vts[(nt * 16 + mrow) * ALD + koff]);
            const bf16x8 v1 = *reinterpret_cast<const bf16x8*>(&Vts[(nt * 16 + mrow) * ALD + 32 + koff]);
            Oacc[nt] = __builtin_amdgcn_mfma_f32_16x16x32_bf16(p0, v0, Oacc[nt], 0, 0, 0);
            Oacc[nt] = __builtin_amdgcn_mfma_f32_16x16x32_bf16(p1, v1, Oacc[nt], 0, 0, 0);
        }
        Lacc = __builtin_amdgcn_mfma_f32_16x16x32_bf16(p0, onesf, Lacc, 0, 0, 0);
        Lacc = __builtin_amdgcn_mfma_f32_16x16x32_bf16(p1, onesf, Lacc, 0, 0, 0);
    }
#undef PREFETCH

    float rl[4];
    #pragma unroll
    for (int reg = 0; reg < 4; reg++) {
        const float lsum = __shfl(Lacc[reg], lane & 48, 64);
        rl[reg] = 1.f / lsum;
    }
    #pragma unroll
    for (int nt = 0; nt < 4; nt++)
        #pragma unroll
        for (int reg = 0; reg < 4; reg++) {
            const int q = qbase + r0 + reg;
            const int d = nt * 16 + col0;
            ctx[((size_t)b * S_ + q) * H_ + h * HD_ + d] = f2bf_rn(Oacc[nt][reg] * rl[reg]);
        }
}

// ---------------------------------------------------------------- launch
extern "C" void kernel_launch(void* const* d_in, const int* in_sizes, int n_in,
                              void* d_out, int out_size, void* d_ws, size_t ws_size,
                              hipStream_t stream) {
    const float* x     = (const float*)d_in[0];
    const int*   mask  = (const int*)d_in[1];
    const float* normw = (const float*)d_in[2];
    const float* normb = (const float*)d_in[3];
    const float* qkvw  = (const float*)d_in[4];
    const float* qkvb  = (const float*)d_in[5];
    const float* ow    = (const float*)d_in[6];
    const float* ob    = (const float*)d_in[7];
    float* out = (float*)d_out;

    char* ws = (char*)d_ws;
    unsigned short* xn_bf   = (unsigned short*)(ws);                      //  8 MB
    unsigned short* qkvwT   = (unsigned short*)(ws + (8ull  << 20));      //  6 MB
    unsigned short* owT     = (unsigned short*)(ws + (14ull << 20));      //  2 MB
    unsigned short* Qb      = (unsigned short*)(ws + (16ull << 20));      //  8 MB [bh][s][d]
    unsigned short* Kb      = (unsigned short*)(ws + (24ull << 20));      //  8 MB [bh][s][d]
    unsigned short* Vtb     = (unsigned short*)(ws + (32ull << 20));      //  8 MB [bh][d][s]
    unsigned short* ctx_bf  = (unsigned short*)(ws + (40ull << 20));      //  8 MB

    cvt_transpose_k<<<dim3(H3_ / 64, H_ / 64), 256, 0, stream>>>(qkvw, qkvwT, H_, H3_);
    cvt_transpose_k<<<dim3(H_  / 64, H_ / 64), 256, 0, stream>>>(ow,   owT,   H_, H_);
    layernorm_k<<<T_, 256, 0, stream>>>(x, normw, normb, xn_bf);
    gemm_qkv_k<<<dim3(H3_ / BN, T_ / BM), 256, 0, stream>>>(xn_bf, qkvwT, qkvb, Qb, Kb, Vtb);
    attn_k<<<1024, 256, 0, stream>>>(Qb, Kb, Vtb, mask, ctx_bf);
    gemm_proj_k<<<dim3(H_ / BN, T_ / BM), 256, 0, stream>>>(ctx_bf, owT, ob, out, T_, H_, H_);
}

// Round 8
// 202.487 us; speedup vs baseline: 1.8468x; 1.0530x over previous
//
#include <hip/hip_runtime.h>
#include <hip/hip_bf16.h>

#define B_  2
#define S_  2048
#define H_  1024
#define NH_ 16
#define HD_ 64
#define T_  (B_*S_)     // 4096 tokens
#define H3_ (3*H_)      // 3072

typedef float  floatx4 __attribute__((ext_vector_type(4)));
typedef __bf16 bf16x8  __attribute__((ext_vector_type(8)));

__device__ inline unsigned short f2bf_rn(float f) {
    union { float f; unsigned int u; } v; v.f = f;
    unsigned int u = v.u;
    u += 0x7fffu + ((u >> 16) & 1u);
    return (unsigned short)(u >> 16);
}
__device__ inline unsigned short f2bf_tr(float f) {   // truncate — self-consistent w/ MFMA-summed l
    union { float f; unsigned int u; } v; v.f = f;
    return (unsigned short)(v.u >> 16);
}
__device__ inline floatx4 fzero4() { floatx4 v; v[0]=0.f; v[1]=0.f; v[2]=0.f; v[3]=0.f; return v; }

// async global->LDS, 16B per lane; LDS dest = wave-uniform base + lane*16
__device__ inline void gload_lds16(const unsigned short* g, unsigned short* l) {
    __builtin_amdgcn_global_load_lds((const __attribute__((address_space(1))) unsigned int*)g,
                                     (__attribute__((address_space(3))) unsigned int*)l,
                                     16, 0, 0);
}

// ---------------------------------------------------------------- fused cast + transpose (both weights, one launch)
#define TLD 72
__global__ __launch_bounds__(256) void cvt_both_k(const float* __restrict__ qkvw,
                                                  const float* __restrict__ ow,
                                                  unsigned short* __restrict__ qkvwT,
                                                  unsigned short* __restrict__ owT) {
    __shared__ unsigned short Ts[64 * TLD];
    int id = blockIdx.x;
    const float* W; unsigned short* Wt; int N, nb, kb;
    if (id < 768) { W = qkvw; Wt = qkvwT; N = H3_; nb = (id % 48) * 64; kb = (id / 48) * 64; }
    else { id -= 768; W = ow; Wt = owT; N = H_; nb = (id % 16) * 64; kb = (id / 16) * 64; }
    const int K = H_;
    const int tid = threadIdx.x;
    #pragma unroll
    for (int p = 0; p < 4; p++) {
        const int krow = kb + p * 16 + (tid >> 4);
        const int ncol = (tid & 15) * 4;
        const float4 w = *reinterpret_cast<const float4*>(&W[(size_t)krow * N + nb + ncol]);
        Ts[(ncol + 0) * TLD + p * 16 + (tid >> 4)] = f2bf_rn(w.x);
        Ts[(ncol + 1) * TLD + p * 16 + (tid >> 4)] = f2bf_rn(w.y);
        Ts[(ncol + 2) * TLD + p * 16 + (tid >> 4)] = f2bf_rn(w.z);
        Ts[(ncol + 3) * TLD + p * 16 + (tid >> 4)] = f2bf_rn(w.w);
    }
    __syncthreads();
    #pragma unroll
    for (int p = 0; p < 2; p++) {
        const int n = (tid >> 3) + p * 32;
        const int k8 = (tid & 7) * 8;
        const uint4 v = *reinterpret_cast<const uint4*>(&Ts[n * TLD + k8]);
        *reinterpret_cast<uint4*>(&Wt[(size_t)(nb + n) * K + kb + k8]) = v;
    }
}

// ---------------------------------------------------------------- LayerNorm (fp32 stats, bf16 out)
__global__ __launch_bounds__(256) void layernorm_k(const float* __restrict__ x,
                                                   const float* __restrict__ w,
                                                   const float* __restrict__ b,
                                                   unsigned short* __restrict__ xn) {
    const int t   = blockIdx.x;
    const int tid = threadIdx.x;
    const float4 v = reinterpret_cast<const float4*>(x + (size_t)t * H_)[tid];
    float s  = v.x + v.y + v.z + v.w;
    float s2 = v.x*v.x + v.y*v.y + v.z*v.z + v.w*v.w;
    for (int off = 32; off > 0; off >>= 1) {
        s  += __shfl_down(s,  off, 64);
        s2 += __shfl_down(s2, off, 64);
    }
    __shared__ float red[8];
    const int wave = tid >> 6, lane = tid & 63;
    if (lane == 0) { red[wave] = s; red[4 + wave] = s2; }
    __syncthreads();
    if (tid == 0) {
        red[0] = red[0] + red[1] + red[2] + red[3];
        red[4] = red[4] + red[5] + red[6] + red[7];
    }
    __syncthreads();
    const float mean = red[0] * (1.f / H_);
    const float var  = red[4] * (1.f / H_) - mean * mean;
    const float rstd = rsqrtf(var + 1e-5f);
    const float4 wv = reinterpret_cast<const float4*>(w)[tid];
    const float4 bv = reinterpret_cast<const float4*>(b)[tid];
    ushort4 o = make_ushort4(f2bf_rn((v.x - mean) * rstd * wv.x + bv.x),
                             f2bf_rn((v.y - mean) * rstd * wv.y + bv.y),
                             f2bf_rn((v.z - mean) * rstd * wv.z + bv.z),
                             f2bf_rn((v.w - mean) * rstd * wv.w + bv.w));
    reinterpret_cast<ushort4*>(xn + (size_t)t * H_)[tid] = o;
}

// ---------------------------------------------------------------- shared GEMM core: BK=64 as two BK=32 sub-buffers
// (global_load_lds forces unpadded rows; 64B-stride sub-buffers keep the free 2-way bank pattern,
//  a monolithic 128B stride would be 16-way conflicted. 32 MFMA per barrier-pair.)
#define BM 128
#define BN 128

__device__ inline void gemm_core(const unsigned short* __restrict__ A,
                                 const unsigned short* __restrict__ Bt,
                                 int K, int mBase, int nBase,
                                 int tid, floatx4 acc[4][4],
                                 unsigned short* As0, unsigned short* As1,
                                 unsigned short* Bs0, unsigned short* Bs1) {
    const int lane = tid & 63;
    const int wave = tid >> 6;
    const int wr = wave >> 1, wc = wave & 1;
    const int srow = lane >> 2;        // 0..15
    const int scol = (lane & 3) * 8;   // 0,8,16,24
    const int mrow = lane & 15;
    const int koff = (lane >> 4) * 8;

    for (int kb = 0; kb < K; kb += 64) {
        __syncthreads();
        #pragma unroll
        for (int p = 0; p < 2; p++) {
            const int r = wave * 16 + p * 64;
            const size_t ga = (size_t)(mBase + r + srow) * K + kb + scol;
            const size_t gb = (size_t)(nBase + r + srow) * K + kb + scol;
            gload_lds16(&A [ga],      &As0[r * 32]);
            gload_lds16(&A [ga + 32], &As1[r * 32]);
            gload_lds16(&Bt[gb],      &Bs0[r * 32]);
            gload_lds16(&Bt[gb + 32], &Bs1[r * 32]);
        }
        __syncthreads();

        #pragma unroll
        for (int half = 0; half < 2; half++) {
            const unsigned short* As = half ? As1 : As0;
            const unsigned short* Bs = half ? Bs1 : Bs0;
            bf16x8 afrag[4], bfrag[4];
            #pragma unroll
            for (int mt = 0; mt < 4; mt++)
                afrag[mt] = *reinterpret_cast<const bf16x8*>(&As[(wr * 64 + mt * 16 + mrow) * 32 + koff]);
            #pragma unroll
            for (int nt = 0; nt < 4; nt++)
                bfrag[nt] = *reinterpret_cast<const bf16x8*>(&Bs[(wc * 64 + nt * 16 + mrow) * 32 + koff]);
            #pragma unroll
            for (int mt = 0; mt < 4; mt++)
                #pragma unroll
                for (int nt = 0; nt < 4; nt++)
                    acc[mt][nt] = __builtin_amdgcn_mfma_f32_16x16x32_bf16(afrag[mt], bfrag[nt], acc[mt][nt], 0, 0, 0);
        }
    }
}

// ---------------------------------------------------------------- QKV GEMM with fused bias+rotary+V-transpose epilogue
__global__ __launch_bounds__(256) void gemm_qkv_k(const unsigned short* __restrict__ A,
                                                  const unsigned short* __restrict__ Bt,
                                                  const float* __restrict__ bias,
                                                  unsigned short* __restrict__ Qo,
                                                  unsigned short* __restrict__ Ko,
                                                  unsigned short* __restrict__ Vto) {
    __shared__ unsigned short As0[BM * 32], As1[BM * 32];
    __shared__ unsigned short Bs0[BN * 32], Bs1[BN * 32];

    const int tid  = threadIdx.x;
    const int lane = tid & 63;
    const int wave = tid >> 6;
    const int wr = wave >> 1, wc = wave & 1;
    const int mBase = blockIdx.y * BM;
    const int nBase = blockIdx.x * BN;

    floatx4 acc[4][4];
    #pragma unroll
    for (int i = 0; i < 4; i++)
        #pragma unroll
        for (int j = 0; j < 4; j++) acc[i][j] = fzero4();

    gemm_core(A, Bt, H_, mBase, nBase, tid, acc, As0, As1, Bs0, Bs1);

    const int col0 = lane & 15;
    const int r0   = (lane >> 4) * 4;
    const int hg   = (nBase + wc * 64) >> 6;   // global head index (wave-uniform)
    const int sec  = hg >> 4;                  // 0=q 1=k 2=v
    const int h    = hg & 15;

    float bs[4];
    #pragma unroll
    for (int nt = 0; nt < 4; nt++) bs[nt] = bias[nBase + wc * 64 + nt * 16 + col0];

    if (sec < 2) {
        unsigned short* dst = (sec == 0) ? Qo : Ko;
        const float if0 = __expf((float)col0        * (-0.2878231366f));   // j = col0
        const float if1 = __expf((float)(16 + col0) * (-0.2878231366f));   // j = 16+col0
        #pragma unroll
        for (int mt = 0; mt < 4; mt++) {
            #pragma unroll
            for (int reg = 0; reg < 4; reg++) {
                const int t  = mBase + wr * 64 + mt * 16 + r0 + reg;
                const int bb = t >> 11;
                const int s  = t & (S_ - 1);
                float sn0, cs0, sn1, cs1;
                __sincosf((float)s * if0, &sn0, &cs0);
                __sincosf((float)s * if1, &sn1, &cs1);
                const float v0 = acc[mt][0][reg] + bs[0];   // d = col0
                const float v1 = acc[mt][1][reg] + bs[1];   // d = 16+col0
                const float v2 = acc[mt][2][reg] + bs[2];   // d = 32+col0
                const float v3 = acc[mt][3][reg] + bs[3];   // d = 48+col0
                const float o0 = v0 * cs0 - v2 * sn0;
                const float o1 = v1 * cs1 - v3 * sn1;
                const float o2 = v2 * cs0 + v0 * sn0;
                const float o3 = v3 * cs1 + v1 * sn1;
                const size_t rb = ((size_t)(bb * NH_ + h) * S_ + s) * HD_;
                dst[rb +      col0] = f2bf_rn(o0);
                dst[rb + 16 + col0] = f2bf_rn(o1);
                dst[rb + 32 + col0] = f2bf_rn(o2);
                dst[rb + 48 + col0] = f2bf_rn(o3);
            }
        }
    } else {
        #pragma unroll
        for (int mt = 0; mt < 4; mt++) {
            const int t0 = mBase + wr * 64 + mt * 16 + r0;   // 4 consecutive tokens, 4-aligned
            const int bb = t0 >> 11;
            const int s0 = t0 & (S_ - 1);
            #pragma unroll
            for (int nt = 0; nt < 4; nt++) {
                const int d = nt * 16 + col0;
                ushort4 o;
                o.x = f2bf_rn(acc[mt][nt][0] + bs[nt]);
                o.y = f2bf_rn(acc[mt][nt][1] + bs[nt]);
                o.z = f2bf_rn(acc[mt][nt][2] + bs[nt]);
                o.w = f2bf_rn(acc[mt][nt][3] + bs[nt]);
                *reinterpret_cast<ushort4*>(&Vto[((size_t)(bb * NH_ + h) * HD_ + d) * S_ + s0]) = o;
            }
        }
    }
}

// ---------------------------------------------------------------- proj GEMM: C = A @ Bt^T + bias (f32 out)
__global__ __launch_bounds__(256) void gemm_proj_k(const unsigned short* __restrict__ A,
                                                   const unsigned short* __restrict__ Bt,
                                                   const float* __restrict__ bias,
                                                   float* __restrict__ Cf,
                                                   int M, int N, int K) {
    __shared__ unsigned short As0[BM * 32], As1[BM * 32];
    __shared__ unsigned short Bs0[BN * 32], Bs1[BN * 32];

    const int tid  = threadIdx.x;
    const int lane = tid & 63;
    const int wave = tid >> 6;
    const int wr = wave >> 1, wc = wave & 1;
    const int mBase = blockIdx.y * BM;
    const int nBase = blockIdx.x * BN;

    floatx4 acc[4][4];
    #pragma unroll
    for (int i = 0; i < 4; i++)
        #pragma unroll
        for (int j = 0; j < 4; j++) acc[i][j] = fzero4();

    gemm_core(A, Bt, K, mBase, nBase, tid, acc, As0, As1, Bs0, Bs1);

    const int col0 = lane & 15;
    const int r0   = (lane >> 4) * 4;
    #pragma unroll
    for (int mt = 0; mt < 4; mt++) {
        #pragma unroll
        for (int nt = 0; nt < 4; nt++) {
            const int gcol = nBase + wc * 64 + nt * 16 + col0;
            const float bsv = bias[gcol];
            #pragma unroll
            for (int reg = 0; reg < 4; reg++) {
                const int grow = mBase + wr * 64 + mt * 16 + r0 + reg;
                Cf[(size_t)grow * N + gcol] = acc[mt][nt][reg] + bsv;
            }
        }
    }
}

// ---------------------------------------------------------------- flash attention (unchanged from R6/R7)
#define ALD 72
#define SCL2 0.1803368801f      /* 0.125 * log2(e) */
#define MNEG -14427.0f          /* -10000 * log2(e), causal fill */

__global__ __launch_bounds__(256, 4) void attn_k(const unsigned short* __restrict__ Q,
                                                 const unsigned short* __restrict__ Kg,
                                                 const unsigned short* __restrict__ Vt,
                                                 const int* __restrict__ mask,
                                                 unsigned short* __restrict__ ctx) {
    const int id = blockIdx.x;              // 0..1023
    const int bh = id & 31;                 // id%8 fixed per bh -> XCD locality
    const int v  = 31 - (id >> 5);          // q-tile index; most work first
    const int b  = bh >> 4;
    const int h  = bh & 15;
    const int tid  = threadIdx.x;
    const int lane = tid & 63;
    const int wave = tid >> 6;

    __shared__ unsigned short Ks [64 * ALD];
    __shared__ unsigned short Vts[64 * ALD];
    __shared__ unsigned short Ps[4][16 * ALD];

    const size_t base = (size_t)bh * S_ * HD_;
    const int qbase = v * 64 + wave * 16;
    const int mrow = lane & 15;
    const int koff = (lane >> 4) * 8;
    const int r0   = (lane >> 4) * 4;
    const int col0 = lane & 15;

    bf16x8 qf0 = *reinterpret_cast<const bf16x8*>(&Q[base + (size_t)(qbase + mrow) * HD_ + koff]);
    bf16x8 qf1 = *reinterpret_cast<const bf16x8*>(&Q[base + (size_t)(qbase + mrow) * HD_ + 32 + koff]);

    bf16x8 onesf;
    {
        const __bf16 ov = (__bf16)((mrow == 0) ? 1.f : 0.f);
        #pragma unroll
        for (int q = 0; q < 8; q++) onesf[q] = ov;
    }

    floatx4 Oacc[4];
    floatx4 Lacc = fzero4();
    #pragma unroll
    for (int nt = 0; nt < 4; nt++) Oacc[nt] = fzero4();

    const int srow = tid >> 3;
    const int scol = (tid & 7) * 8;

    uint4 kreg0, kreg1, vreg0, vreg1;
    float mb0, mb1, mb2, mb3;
#define PREFETCH(KT) do {                                                                      \
        const int kb_ = (KT) * 64;                                                             \
        kreg0 = *reinterpret_cast<const uint4*>(&Kg[base + (size_t)(kb_ + srow)      * HD_ + scol]); \
        kreg1 = *reinterpret_cast<const uint4*>(&Kg[base + (size_t)(kb_ + srow + 32) * HD_ + scol]); \
        vreg0 = *reinterpret_cast<const uint4*>(&Vt[base + (size_t)srow        * S_ + kb_ + scol]);  \
        vreg1 = *reinterpret_cast<const uint4*>(&Vt[base + (size_t)(srow + 32) * S_ + kb_ + scol]);  \
        mb0 = (1.f - (float)mask[b * S_ + kb_ +  0 + col0]) * MNEG;                            \
        mb1 = (1.f - (float)mask[b * S_ + kb_ + 16 + col0]) * MNEG;                            \
        mb2 = (1.f - (float)mask[b * S_ + kb_ + 32 + col0]) * MNEG;                            \
        mb3 = (1.f - (float)mask[b * S_ + kb_ + 48 + col0]) * MNEG;                            \
    } while (0)

    PREFETCH(0);

    unsigned short* pw = Ps[wave];

    for (int kt = 0; kt <= v; kt++) {
        const int kb = kt * 64;
        if (kt) __syncthreads();
        *reinterpret_cast<uint4*>(&Ks [ srow       * ALD + scol]) = kreg0;
        *reinterpret_cast<uint4*>(&Ks [(srow + 32) * ALD + scol]) = kreg1;
        *reinterpret_cast<uint4*>(&Vts[ srow       * ALD + scol]) = vreg0;
        *reinterpret_cast<uint4*>(&Vts[(srow + 32) * ALD + scol]) = vreg1;
        __syncthreads();
        const float mc0 = mb0, mc1 = mb1, mc2 = mb2, mc3 = mb3;
        if (kt < v) PREFETCH(kt + 1);

        floatx4 sc[4];
        #pragma unroll
        for (int nt = 0; nt < 4; nt++) {
            const bf16x8 k0 = *reinterpret_cast<const bf16x8*>(&Ks[(nt * 16 + mrow) * ALD + koff]);
            const bf16x8 k1 = *reinterpret_cast<const bf16x8*>(&Ks[(nt * 16 + mrow) * ALD + 32 + koff]);
            floatx4 c = fzero4();
            c = __builtin_amdgcn_mfma_f32_16x16x32_bf16(qf0, k0, c, 0, 0, 0);
            c = __builtin_amdgcn_mfma_f32_16x16x32_bf16(qf1, k1, c, 0, 0, 0);
            sc[nt] = c;
        }
        #pragma unroll
        for (int nt = 0; nt < 4; nt++) {
            const float mbv = (nt == 0) ? mc0 : (nt == 1) ? mc1 : (nt == 2) ? mc2 : mc3;
            #pragma unroll
            for (int reg = 0; reg < 4; reg++)
                sc[nt][reg] = sc[nt][reg] * SCL2 + mbv;
        }
        if (kt == v) {
            #pragma unroll
            for (int nt = 0; nt < 4; nt++) {
                const int key = kb + nt * 16 + col0;
                #pragma unroll
                for (int reg = 0; reg < 4; reg++)
                    if (key > qbase + r0 + reg) sc[nt][reg] = MNEG;
            }
        }
        #pragma unroll
        for (int nt = 0; nt < 4; nt++)
            #pragma unroll
            for (int reg = 0; reg < 4; reg++)
                pw[(r0 + reg) * ALD + nt * 16 + col0] = f2bf_tr(exp2f(sc[nt][reg]));
        const bf16x8 p0 = *reinterpret_cast<const bf16x8*>(&pw[mrow * ALD + koff]);
        const bf16x8 p1 = *reinterpret_cast<const bf16x8*>(&pw[mrow * ALD + 32 + koff]);
        #pragma unroll
        for (int nt = 0; nt < 4; nt++) {
            const bf16x8 v0 = *reinterpret_cast<const bf16x8*>(&Vts[(nt * 16 + mrow) * ALD + koff]);
            const bf16x8 v1 = *reinterpret_cast<const bf16x8*>(&Vts[(nt * 16 + mrow) * ALD + 32 + koff]);
            Oacc[nt] = __builtin_amdgcn_mfma_f32_16x16x32_bf16(p0, v0, Oacc[nt], 0, 0, 0);
            Oacc[nt] = __builtin_amdgcn_mfma_f32_16x16x32_bf16(p1, v1, Oacc[nt], 0, 0, 0);
        }
        Lacc = __builtin_amdgcn_mfma_f32_16x16x32_bf16(p0, onesf, Lacc, 0, 0, 0);
        Lacc = __builtin_amdgcn_mfma_f32_16x16x32_bf16(p1, onesf, Lacc, 0, 0, 0);
    }
#undef PREFETCH

    float rl[4];
    #pragma unroll
    for (int reg = 0; reg < 4; reg++) {
        const float lsum = __shfl(Lacc[reg], lane & 48, 64);
        rl[reg] = 1.f / lsum;
    }
    #pragma unroll
    for (int nt = 0; nt < 4; nt++)
        #pragma unroll
        for (int reg = 0; reg < 4; reg++) {
            const int q = qbase + r0 + reg;
            const int d = nt * 16 + col0;
            ctx[((size_t)b * S_ + q) * H_ + h * HD_ + d] = f2bf_rn(Oacc[nt][reg] * rl[reg]);
        }
}

// ---------------------------------------------------------------- launch
extern "C" void kernel_launch(void* const* d_in, const int* in_sizes, int n_in,
                              void* d_out, int out_size, void* d_ws, size_t ws_size,
                              hipStream_t stream) {
    const float* x     = (const float*)d_in[0];
    const int*   mask  = (const int*)d_in[1];
    const float* normw = (const float*)d_in[2];
    const float* normb = (const float*)d_in[3];
    const float* qkvw  = (const float*)d_in[4];
    const float* qkvb  = (const float*)d_in[5];
    const float* ow    = (const float*)d_in[6];
    const float* ob    = (const float*)d_in[7];
    float* out = (float*)d_out;

    char* ws = (char*)d_ws;
    unsigned short* xn_bf   = (unsigned short*)(ws);                      //  8 MB
    unsigned short* qkvwT   = (unsigned short*)(ws + (8ull  << 20));      //  6 MB
    unsigned short* owT     = (unsigned short*)(ws + (14ull << 20));      //  2 MB
    unsigned short* Qb      = (unsigned short*)(ws + (16ull << 20));      //  8 MB [bh][s][d]
    unsigned short* Kb      = (unsigned short*)(ws + (24ull << 20));      //  8 MB [bh][s][d]
    unsigned short* Vtb     = (unsigned short*)(ws + (32ull << 20));      //  8 MB [bh][d][s]
    unsigned short* ctx_bf  = (unsigned short*)(ws + (40ull << 20));      //  8 MB

    cvt_both_k<<<1024, 256, 0, stream>>>(qkvw, ow, qkvwT, owT);
    layernorm_k<<<T_, 256, 0, stream>>>(x, normw, normb, xn_bf);
    gemm_qkv_k<<<dim3(H3_ / BN, T_ / BM), 256, 0, stream>>>(xn_bf, qkvwT, qkvb, Qb, Kb, Vtb);
    attn_k<<<1024, 256, 0, stream>>>(Qb, Kb, Vtb, mask, ctx_bf);
    gemm_proj_k<<<dim3(H_ / BN, T_ / BM), 256, 0, stream>>>(ctx_bf, owT, ob, out, T_, H_, H_);
}

// Round 9
// 199.091 us; speedup vs baseline: 1.8783x; 1.0171x over previous
//
#include <hip/hip_runtime.h>
#include <hip/hip_bf16.h>

#define B_  2
#define S_  2048
#define H_  1024
#define NH_ 16
#define HD_ 64
#define T_  (B_*S_)     // 4096 tokens
#define H3_ (3*H_)      // 3072

typedef float  floatx4 __attribute__((ext_vector_type(4)));
typedef __bf16 bf16x8  __attribute__((ext_vector_type(8)));

__device__ inline unsigned short f2bf_rn(float f) {
    union { float f; unsigned int u; } v; v.f = f;
    unsigned int u = v.u;
    u += 0x7fffu + ((u >> 16) & 1u);
    return (unsigned short)(u >> 16);
}
__device__ inline unsigned short f2bf_tr(float f) {   // truncate — self-consistent w/ MFMA-summed l
    union { float f; unsigned int u; } v; v.f = f;
    return (unsigned short)(v.u >> 16);
}
__device__ inline floatx4 fzero4() { floatx4 v; v[0]=0.f; v[1]=0.f; v[2]=0.f; v[3]=0.f; return v; }

// async global->LDS, 16B per lane; LDS dest = wave-uniform base + lane*16
__device__ inline void gload_lds16(const unsigned short* g, unsigned short* l) {
    __builtin_amdgcn_global_load_lds((const __attribute__((address_space(1))) unsigned int*)g,
                                     (__attribute__((address_space(3))) unsigned int*)l,
                                     16, 0, 0);
}

// ---------------------------------------------------------------- fused cast + transpose (both weights, one launch)
#define TLD 72
__global__ __launch_bounds__(256) void cvt_both_k(const float* __restrict__ qkvw,
                                                  const float* __restrict__ ow,
                                                  unsigned short* __restrict__ qkvwT,
                                                  unsigned short* __restrict__ owT) {
    __shared__ unsigned short Ts[64 * TLD];
    int id = blockIdx.x;
    const float* W; unsigned short* Wt; int N, nb, kb;
    if (id < 768) { W = qkvw; Wt = qkvwT; N = H3_; nb = (id % 48) * 64; kb = (id / 48) * 64; }
    else { id -= 768; W = ow; Wt = owT; N = H_; nb = (id % 16) * 64; kb = (id / 16) * 64; }
    const int K = H_;
    const int tid = threadIdx.x;
    #pragma unroll
    for (int p = 0; p < 4; p++) {
        const int krow = kb + p * 16 + (tid >> 4);
        const int ncol = (tid & 15) * 4;
        const float4 w = *reinterpret_cast<const float4*>(&W[(size_t)krow * N + nb + ncol]);
        Ts[(ncol + 0) * TLD + p * 16 + (tid >> 4)] = f2bf_rn(w.x);
        Ts[(ncol + 1) * TLD + p * 16 + (tid >> 4)] = f2bf_rn(w.y);
        Ts[(ncol + 2) * TLD + p * 16 + (tid >> 4)] = f2bf_rn(w.z);
        Ts[(ncol + 3) * TLD + p * 16 + (tid >> 4)] = f2bf_rn(w.w);
    }
    __syncthreads();
    #pragma unroll
    for (int p = 0; p < 2; p++) {
        const int n = (tid >> 3) + p * 32;
        const int k8 = (tid & 7) * 8;
        const uint4 v = *reinterpret_cast<const uint4*>(&Ts[n * TLD + k8]);
        *reinterpret_cast<uint4*>(&Wt[(size_t)(nb + n) * K + kb + k8]) = v;
    }
}

// ---------------------------------------------------------------- LayerNorm (fp32 stats, bf16 out)
__global__ __launch_bounds__(256) void layernorm_k(const float* __restrict__ x,
                                                   const float* __restrict__ w,
                                                   const float* __restrict__ b,
                                                   unsigned short* __restrict__ xn) {
    const int t   = blockIdx.x;
    const int tid = threadIdx.x;
    const float4 v = reinterpret_cast<const float4*>(x + (size_t)t * H_)[tid];
    float s  = v.x + v.y + v.z + v.w;
    float s2 = v.x*v.x + v.y*v.y + v.z*v.z + v.w*v.w;
    for (int off = 32; off > 0; off >>= 1) {
        s  += __shfl_down(s,  off, 64);
        s2 += __shfl_down(s2, off, 64);
    }
    __shared__ float red[8];
    const int wave = tid >> 6, lane = tid & 63;
    if (lane == 0) { red[wave] = s; red[4 + wave] = s2; }
    __syncthreads();
    if (tid == 0) {
        red[0] = red[0] + red[1] + red[2] + red[3];
        red[4] = red[4] + red[5] + red[6] + red[7];
    }
    __syncthreads();
    const float mean = red[0] * (1.f / H_);
    const float var  = red[4] * (1.f / H_) - mean * mean;
    const float rstd = rsqrtf(var + 1e-5f);
    const float4 wv = reinterpret_cast<const float4*>(w)[tid];
    const float4 bv = reinterpret_cast<const float4*>(b)[tid];
    ushort4 o = make_ushort4(f2bf_rn((v.x - mean) * rstd * wv.x + bv.x),
                             f2bf_rn((v.y - mean) * rstd * wv.y + bv.y),
                             f2bf_rn((v.z - mean) * rstd * wv.z + bv.z),
                             f2bf_rn((v.w - mean) * rstd * wv.w + bv.w));
    reinterpret_cast<ushort4*>(xn + (size_t)t * H_)[tid] = o;
}

// ---------------------------------------------------------------- shared GEMM core: BK=64 as two BK=32 sub-buffers
#define BM 128
#define BN 128

__device__ inline void gemm_core(const unsigned short* __restrict__ A,
                                 const unsigned short* __restrict__ Bt,
                                 int K, int mBase, int nBase,
                                 int tid, floatx4 acc[4][4],
                                 unsigned short* As0, unsigned short* As1,
                                 unsigned short* Bs0, unsigned short* Bs1) {
    const int lane = tid & 63;
    const int wave = tid >> 6;
    const int wr = wave >> 1, wc = wave & 1;
    const int srow = lane >> 2;        // 0..15
    const int scol = (lane & 3) * 8;   // 0,8,16,24
    const int mrow = lane & 15;
    const int koff = (lane >> 4) * 8;

    for (int kb = 0; kb < K; kb += 64) {
        __syncthreads();
        #pragma unroll
        for (int p = 0; p < 2; p++) {
            const int r = wave * 16 + p * 64;
            const size_t ga = (size_t)(mBase + r + srow) * K + kb + scol;
            const size_t gb = (size_t)(nBase + r + srow) * K + kb + scol;
            gload_lds16(&A [ga],      &As0[r * 32]);
            gload_lds16(&A [ga + 32], &As1[r * 32]);
            gload_lds16(&Bt[gb],      &Bs0[r * 32]);
            gload_lds16(&Bt[gb + 32], &Bs1[r * 32]);
        }
        __syncthreads();

        #pragma unroll
        for (int half = 0; half < 2; half++) {
            const unsigned short* As = half ? As1 : As0;
            const unsigned short* Bs = half ? Bs1 : Bs0;
            bf16x8 afrag[4], bfrag[4];
            #pragma unroll
            for (int mt = 0; mt < 4; mt++)
                afrag[mt] = *reinterpret_cast<const bf16x8*>(&As[(wr * 64 + mt * 16 + mrow) * 32 + koff]);
            #pragma unroll
            for (int nt = 0; nt < 4; nt++)
                bfrag[nt] = *reinterpret_cast<const bf16x8*>(&Bs[(wc * 64 + nt * 16 + mrow) * 32 + koff]);
            #pragma unroll
            for (int mt = 0; mt < 4; mt++)
                #pragma unroll
                for (int nt = 0; nt < 4; nt++)
                    acc[mt][nt] = __builtin_amdgcn_mfma_f32_16x16x32_bf16(afrag[mt], bfrag[nt], acc[mt][nt], 0, 0, 0);
        }
    }
}

// ---------------------------------------------------------------- QKV GEMM with fused bias+rotary+V-transpose epilogue
__global__ __launch_bounds__(256) void gemm_qkv_k(const unsigned short* __restrict__ A,
                                                  const unsigned short* __restrict__ Bt,
                                                  const float* __restrict__ bias,
                                                  unsigned short* __restrict__ Qo,
                                                  unsigned short* __restrict__ Ko,
                                                  unsigned short* __restrict__ Vto) {
    __shared__ unsigned short As0[BM * 32], As1[BM * 32];
    __shared__ unsigned short Bs0[BN * 32], Bs1[BN * 32];

    const int tid  = threadIdx.x;
    const int lane = tid & 63;
    const int wave = tid >> 6;
    const int wr = wave >> 1, wc = wave & 1;
    const int mBase = blockIdx.y * BM;
    const int nBase = blockIdx.x * BN;

    floatx4 acc[4][4];
    #pragma unroll
    for (int i = 0; i < 4; i++)
        #pragma unroll
        for (int j = 0; j < 4; j++) acc[i][j] = fzero4();

    gemm_core(A, Bt, H_, mBase, nBase, tid, acc, As0, As1, Bs0, Bs1);

    const int col0 = lane & 15;
    const int r0   = (lane >> 4) * 4;
    const int hg   = (nBase + wc * 64) >> 6;   // global head index (wave-uniform)
    const int sec  = hg >> 4;                  // 0=q 1=k 2=v
    const int h    = hg & 15;

    float bs[4];
    #pragma unroll
    for (int nt = 0; nt < 4; nt++) bs[nt] = bias[nBase + wc * 64 + nt * 16 + col0];

    if (sec < 2) {
        unsigned short* dst = (sec == 0) ? Qo : Ko;
        const float if0 = __expf((float)col0        * (-0.2878231366f));   // j = col0
        const float if1 = __expf((float)(16 + col0) * (-0.2878231366f));   // j = 16+col0
        #pragma unroll
        for (int mt = 0; mt < 4; mt++) {
            #pragma unroll
            for (int reg = 0; reg < 4; reg++) {
                const int t  = mBase + wr * 64 + mt * 16 + r0 + reg;
                const int bb = t >> 11;
                const int s  = t & (S_ - 1);
                float sn0, cs0, sn1, cs1;
                __sincosf((float)s * if0, &sn0, &cs0);
                __sincosf((float)s * if1, &sn1, &cs1);
                const float v0 = acc[mt][0][reg] + bs[0];   // d = col0
                const float v1 = acc[mt][1][reg] + bs[1];   // d = 16+col0
                const float v2 = acc[mt][2][reg] + bs[2];   // d = 32+col0
                const float v3 = acc[mt][3][reg] + bs[3];   // d = 48+col0
                const float o0 = v0 * cs0 - v2 * sn0;
                const float o1 = v1 * cs1 - v3 * sn1;
                const float o2 = v2 * cs0 + v0 * sn0;
                const float o3 = v3 * cs1 + v1 * sn1;
                const size_t rb = ((size_t)(bb * NH_ + h) * S_ + s) * HD_;
                dst[rb +      col0] = f2bf_rn(o0);
                dst[rb + 16 + col0] = f2bf_rn(o1);
                dst[rb + 32 + col0] = f2bf_rn(o2);
                dst[rb + 48 + col0] = f2bf_rn(o3);
            }
        }
    } else {
        #pragma unroll
        for (int mt = 0; mt < 4; mt++) {
            const int t0 = mBase + wr * 64 + mt * 16 + r0;   // 4 consecutive tokens, 4-aligned
            const int bb = t0 >> 11;
            const int s0 = t0 & (S_ - 1);
            #pragma unroll
            for (int nt = 0; nt < 4; nt++) {
                const int d = nt * 16 + col0;
                ushort4 o;
                o.x = f2bf_rn(acc[mt][nt][0] + bs[nt]);
                o.y = f2bf_rn(acc[mt][nt][1] + bs[nt]);
                o.z = f2bf_rn(acc[mt][nt][2] + bs[nt]);
                o.w = f2bf_rn(acc[mt][nt][3] + bs[nt]);
                *reinterpret_cast<ushort4*>(&Vto[((size_t)(bb * NH_ + h) * HD_ + d) * S_ + s0]) = o;
            }
        }
    }
}

// ---------------------------------------------------------------- proj GEMM: C = A @ Bt^T + bias (f32 out)
__global__ __launch_bounds__(256) void gemm_proj_k(const unsigned short* __restrict__ A,
                                                   const unsigned short* __restrict__ Bt,
                                                   const float* __restrict__ bias,
                                                   float* __restrict__ Cf,
                                                   int M, int N, int K) {
    __shared__ unsigned short As0[BM * 32], As1[BM * 32];
    __shared__ unsigned short Bs0[BN * 32], Bs1[BN * 32];

    const int tid  = threadIdx.x;
    const int lane = tid & 63;
    const int wave = tid >> 6;
    const int wr = wave >> 1, wc = wave & 1;
    const int mBase = blockIdx.y * BM;
    const int nBase = blockIdx.x * BN;

    floatx4 acc[4][4];
    #pragma unroll
    for (int i = 0; i < 4; i++)
        #pragma unroll
        for (int j = 0; j < 4; j++) acc[i][j] = fzero4();

    gemm_core(A, Bt, K, mBase, nBase, tid, acc, As0, As1, Bs0, Bs1);

    const int col0 = lane & 15;
    const int r0   = (lane >> 4) * 4;
    #pragma unroll
    for (int mt = 0; mt < 4; mt++) {
        #pragma unroll
        for (int nt = 0; nt < 4; nt++) {
            const int gcol = nBase + wc * 64 + nt * 16 + col0;
            const float bsv = bias[gcol];
            #pragma unroll
            for (int reg = 0; reg < 4; reg++) {
                const int grow = mBase + wr * 64 + mt * 16 + r0 + reg;
                Cf[(size_t)grow * N + gcol] = acc[mt][nt][reg] + bsv;
            }
        }
    }
}

// ---------------------------------------------------------------- flash attention: 128-key macro-tiles
// fixed-max log2-softmax, l via MFMA ones-column; 2 barriers per 128 keys (halved fixed cost);
// LDS 45KB -> 3 blocks/CU; inactive half skipped wave-uniformly, its loads clamped in-bounds.
#define ALD 72
#define SCL2 0.1803368801f      /* 0.125 * log2(e) */
#define MNEG -14427.0f          /* -10000 * log2(e), causal fill */

__global__ __launch_bounds__(256, 3) void attn_k(const unsigned short* __restrict__ Q,
                                                 const unsigned short* __restrict__ Kg,
                                                 const unsigned short* __restrict__ Vt,
                                                 const int* __restrict__ mask,
                                                 unsigned short* __restrict__ ctx) {
    const int id = blockIdx.x;              // 0..1023
    const int bh = id & 31;                 // id%8 fixed per bh -> XCD locality
    const int v  = 31 - (id >> 5);          // q-tile index; most work first
    const int b  = bh >> 4;
    const int h  = bh & 15;
    const int tid  = threadIdx.x;
    const int lane = tid & 63;
    const int wave = tid >> 6;

    __shared__ unsigned short Ks [2][64 * ALD];   // 18.4 KB
    __shared__ unsigned short Vts[2][64 * ALD];   // 18.4 KB
    __shared__ unsigned short Ps[4][16 * ALD];    //  9.2 KB -> 45 KB total

    const size_t base = (size_t)bh * S_ * HD_;
    const int qbase = v * 64 + wave * 16;
    const int mrow = lane & 15;
    const int koff = (lane >> 4) * 8;
    const int r0   = (lane >> 4) * 4;
    const int col0 = lane & 15;

    bf16x8 qf0 = *reinterpret_cast<const bf16x8*>(&Q[base + (size_t)(qbase + mrow) * HD_ + koff]);
    bf16x8 qf1 = *reinterpret_cast<const bf16x8*>(&Q[base + (size_t)(qbase + mrow) * HD_ + 32 + koff]);

    bf16x8 onesf;
    {
        const __bf16 ov = (__bf16)((mrow == 0) ? 1.f : 0.f);
        #pragma unroll
        for (int q = 0; q < 8; q++) onesf[q] = ov;
    }

    floatx4 Oacc[4];
    floatx4 Lacc = fzero4();
    #pragma unroll
    for (int nt = 0; nt < 4; nt++) Oacc[nt] = fzero4();

    const int srow = tid >> 3;          // 0..31
    const int scol = (tid & 7) * 8;

    // named prefetch registers for 2 tiles (no runtime-indexed arrays -> no scratch)
    uint4 k00, k01, k10, k11, v00, v01, v10, v11;
    float mb00, mb01, mb02, mb03, mb10, mb11, mb12, mb13;
#define PF_TILE(TT, KR0, KR1, VR0, VR1, M0, M1, M2, M3) do {                                   \
        const int kb_ = (TT) * 64;                                                             \
        KR0 = *reinterpret_cast<const uint4*>(&Kg[base + (size_t)(kb_ + srow)      * HD_ + scol]); \
        KR1 = *reinterpret_cast<const uint4*>(&Kg[base + (size_t)(kb_ + srow + 32) * HD_ + scol]); \
        VR0 = *reinterpret_cast<const uint4*>(&Vt[base + (size_t)srow        * S_ + kb_ + scol]);  \
        VR1 = *reinterpret_cast<const uint4*>(&Vt[base + (size_t)(srow + 32) * S_ + kb_ + scol]);  \
        M0 = (1.f - (float)mask[b * S_ + kb_ +  0 + col0]) * MNEG;                             \
        M1 = (1.f - (float)mask[b * S_ + kb_ + 16 + col0]) * MNEG;                             \
        M2 = (1.f - (float)mask[b * S_ + kb_ + 32 + col0]) * MNEG;                             \
        M3 = (1.f - (float)mask[b * S_ + kb_ + 48 + col0]) * MNEG;                             \
    } while (0)
#define PREFETCH_MACRO(MI) do {                                                                \
        const int t0_ = min(2 * (MI), v);                                                      \
        const int t1_ = min(2 * (MI) + 1, v);                                                  \
        PF_TILE(t0_, k00, k01, v00, v01, mb00, mb01, mb02, mb03);                              \
        PF_TILE(t1_, k10, k11, v10, v11, mb10, mb11, mb12, mb13);                              \
    } while (0)

    const int nmac = (v + 2) >> 1;
    PREFETCH_MACRO(0);

    unsigned short* pw = Ps[wave];

    for (int mi = 0; mi < nmac; mi++) {
        if (mi) __syncthreads();                       // WAR: prior macro's LDS reads done
        *reinterpret_cast<uint4*>(&Ks [0][ srow       * ALD + scol]) = k00;
        *reinterpret_cast<uint4*>(&Ks [0][(srow + 32) * ALD + scol]) = k01;
        *reinterpret_cast<uint4*>(&Ks [1][ srow       * ALD + scol]) = k10;
        *reinterpret_cast<uint4*>(&Ks [1][(srow + 32) * ALD + scol]) = k11;
        *reinterpret_cast<uint4*>(&Vts[0][ srow       * ALD + scol]) = v00;
        *reinterpret_cast<uint4*>(&Vts[0][(srow + 32) * ALD + scol]) = v01;
        *reinterpret_cast<uint4*>(&Vts[1][ srow       * ALD + scol]) = v10;
        *reinterpret_cast<uint4*>(&Vts[1][(srow + 32) * ALD + scol]) = v11;
        __syncthreads();                               // staged tiles visible
        const float mc00 = mb00, mc01 = mb01, mc02 = mb02, mc03 = mb03;
        const float mc10 = mb10, mc11 = mb11, mc12 = mb12, mc13 = mb13;
        if (mi + 1 < nmac) PREFETCH_MACRO(mi + 1);

        #pragma unroll
        for (int half = 0; half < 2; half++) {
            const int kt = 2 * mi + half;
            if (half && kt > v) continue;              // wave-uniform skip (odd tile count)
            const int kb = kt * 64;
            const unsigned short* ks = Ks [half];
            const unsigned short* vs = Vts[half];
            const float c0 = half ? mc10 : mc00;
            const float c1 = half ? mc11 : mc01;
            const float c2 = half ? mc12 : mc02;
            const float c3 = half ? mc13 : mc03;

            // ---- S = Q K^T, scale+bias in log2 domain
            floatx4 sc[4];
            #pragma unroll
            for (int nt = 0; nt < 4; nt++) {
                const bf16x8 kf0 = *reinterpret_cast<const bf16x8*>(&ks[(nt * 16 + mrow) * ALD + koff]);
                const bf16x8 kf1 = *reinterpret_cast<const bf16x8*>(&ks[(nt * 16 + mrow) * ALD + 32 + koff]);
                floatx4 c = fzero4();
                c = __builtin_amdgcn_mfma_f32_16x16x32_bf16(qf0, kf0, c, 0, 0, 0);
                c = __builtin_amdgcn_mfma_f32_16x16x32_bf16(qf1, kf1, c, 0, 0, 0);
                sc[nt] = c;
            }
            #pragma unroll
            for (int nt = 0; nt < 4; nt++) {
                const float mbv = (nt == 0) ? c0 : (nt == 1) ? c1 : (nt == 2) ? c2 : c3;
                #pragma unroll
                for (int reg = 0; reg < 4; reg++)
                    sc[nt][reg] = sc[nt][reg] * SCL2 + mbv;
            }
            // ---- causal (diagonal tile only; wave-uniform branch)
            if (kt == v) {
                #pragma unroll
                for (int nt = 0; nt < 4; nt++) {
                    const int key = kb + nt * 16 + col0;
                    #pragma unroll
                    for (int reg = 0; reg < 4; reg++)
                        if (key > qbase + r0 + reg) sc[nt][reg] = MNEG;
                }
            }
            // ---- P = exp2(s), truncate-store to LDS (A-layout rows)
            #pragma unroll
            for (int nt = 0; nt < 4; nt++)
                #pragma unroll
                for (int reg = 0; reg < 4; reg++)
                    pw[(r0 + reg) * ALD + nt * 16 + col0] = f2bf_tr(exp2f(sc[nt][reg]));
            // ---- PV (+ ones-column for denominator)
            const bf16x8 p0 = *reinterpret_cast<const bf16x8*>(&pw[mrow * ALD + koff]);
            const bf16x8 p1 = *reinterpret_cast<const bf16x8*>(&pw[mrow * ALD + 32 + koff]);
            #pragma unroll
            for (int nt = 0; nt < 4; nt++) {
                const bf16x8 vf0 = *reinterpret_cast<const bf16x8*>(&vs[(nt * 16 + mrow) * ALD + koff]);
                const bf16x8 vf1 = *reinterpret_cast<const bf16x8*>(&vs[(nt * 16 + mrow) * ALD + 32 + koff]);
                Oacc[nt] = __builtin_amdgcn_mfma_f32_16x16x32_bf16(p0, vf0, Oacc[nt], 0, 0, 0);
                Oacc[nt] = __builtin_amdgcn_mfma_f32_16x16x32_bf16(p1, vf1, Oacc[nt], 0, 0, 0);
            }
            Lacc = __builtin_amdgcn_mfma_f32_16x16x32_bf16(p0, onesf, Lacc, 0, 0, 0);
            Lacc = __builtin_amdgcn_mfma_f32_16x16x32_bf16(p1, onesf, Lacc, 0, 0, 0);
        }
    }
#undef PREFETCH_MACRO
#undef PF_TILE

    // epilogue: denominator lives in column 0 lanes (quad*16); broadcast + scale + store
    float rl[4];
    #pragma unroll
    for (int reg = 0; reg < 4; reg++) {
        const float lsum = __shfl(Lacc[reg], lane & 48, 64);
        rl[reg] = 1.f / lsum;
    }
    #pragma unroll
    for (int nt = 0; nt < 4; nt++)
        #pragma unroll
        for (int reg = 0; reg < 4; reg++) {
            const int q = qbase + r0 + reg;
            const int d = nt * 16 + col0;
            ctx[((size_t)b * S_ + q) * H_ + h * HD_ + d] = f2bf_rn(Oacc[nt][reg] * rl[reg]);
        }
}

// ---------------------------------------------------------------- launch
extern "C" void kernel_launch(void* const* d_in, const int* in_sizes, int n_in,
                              void* d_out, int out_size, void* d_ws, size_t ws_size,
                              hipStream_t stream) {
    const float* x     = (const float*)d_in[0];
    const int*   mask  = (const int*)d_in[1];
    const float* normw = (const float*)d_in[2];
    const float* normb = (const float*)d_in[3];
    const float* qkvw  = (const float*)d_in[4];
    const float* qkvb  = (const float*)d_in[5];
    const float* ow    = (const float*)d_in[6];
    const float* ob    = (const float*)d_in[7];
    float* out = (float*)d_out;

    char* ws = (char*)d_ws;
    unsigned short* xn_bf   = (unsigned short*)(ws);                      //  8 MB
    unsigned short* qkvwT   = (unsigned short*)(ws + (8ull  << 20));      //  6 MB
    unsigned short* owT     = (unsigned short*)(ws + (14ull << 20));      //  2 MB
    unsigned short* Qb      = (unsigned short*)(ws + (16ull << 20));      //  8 MB [bh][s][d]
    unsigned short* Kb      = (unsigned short*)(ws + (24ull << 20));      //  8 MB [bh][s][d]
    unsigned short* Vtb     = (unsigned short*)(ws + (32ull << 20));      //  8 MB [bh][d][s]
    unsigned short* ctx_bf  = (unsigned short*)(ws + (40ull << 20));      //  8 MB

    cvt_both_k<<<1024, 256, 0, stream>>>(qkvw, ow, qkvwT, owT);
    layernorm_k<<<T_, 256, 0, stream>>>(x, normw, normb, xn_bf);
    gemm_qkv_k<<<dim3(H3_ / BN, T_ / BM), 256, 0, stream>>>(xn_bf, qkvwT, qkvb, Qb, Kb, Vtb);
    attn_k<<<1024, 256, 0, stream>>>(Qb, Kb, Vtb, mask, ctx_bf);
    gemm_proj_k<<<dim3(H_ / BN, T_ / BM), 256, 0, stream>>>(ctx_bf, owT, ob, out, T_, H_, H_);
}